// Round 1
// baseline (5798.035 us; speedup 1.0000x reference)
//
#include <hip/hip_runtime.h>
#include <hip/hip_bf16.h>
#include <cstdint>

#define N_NODES 100000
#define N_EDGES 1600000
#define DIM 128
#define ODIM 64
#define NPB 64          // nodes per block in GEMM kernels
#define SR 132          // padded LDS row stride (floats)

// ---------------- degree ----------------
__global__ __launch_bounds__(256) void k_deg(const int* __restrict__ dst,
                                             float* __restrict__ deg) {
  int e = blockIdx.x * 256 + threadIdx.x;
  if (e < N_EDGES) atomicAdd(&deg[dst[e]], 1.0f);
}

__global__ __launch_bounds__(256) void k_invdeg(float* __restrict__ deg) {
  int i = blockIdx.x * 256 + threadIdx.x;
  if (i < N_NODES) deg[i] = 1.0f / fmaxf(deg[i], 1.0f);
}

// ---------------- scatter-add aggregation ----------------
// 32 lanes per edge; each lane handles one float4 of the 128-float row.
__global__ __launch_bounds__(256) void k_scatter(const float* __restrict__ feat,
                                                 const int* __restrict__ src,
                                                 const int* __restrict__ dst,
                                                 float* __restrict__ agg) {
  long long gid = (long long)blockIdx.x * 256 + threadIdx.x;
  int e = (int)(gid >> 5);
  if (e >= N_EDGES) return;
  int lane = (int)(gid & 31);
  int s = src[e], d = dst[e];
  float4 v = ((const float4*)(feat + (size_t)s * DIM))[lane];
  float* p = agg + (size_t)d * DIM + lane * 4;
  atomicAdd(p + 0, v.x);
  atomicAdd(p + 1, v.y);
  atomicAdd(p + 2, v.z);
  atomicAdd(p + 3, v.w);
}

// ---------------- fused SAGE layer: h = relu(agg*invdeg @ w_l + b + x @ w_r) ----------------
__global__ __launch_bounds__(256) void k_sage(const float* __restrict__ agg,
                                              const float* __restrict__ xin,
                                              const float* __restrict__ invdeg,
                                              const float* __restrict__ w_l,
                                              const float* __restrict__ b_l,
                                              const float* __restrict__ w_r,
                                              float* __restrict__ hout) {
  __shared__ float sA[NPB * SR];
  __shared__ float sX[NPB * SR];
  const int tid = threadIdx.x;
  const int base = blockIdx.x * NPB;

  // stage 64 node rows of agg (scaled by invdeg) and x into LDS
  for (int t = tid; t < NPB * 32; t += 256) {
    int r = t >> 5, c = t & 31;
    int n = base + r;
    float4 va = make_float4(0.f, 0.f, 0.f, 0.f);
    float4 vx = va;
    float s = 0.f;
    if (n < N_NODES) {
      s = invdeg[n];
      va = ((const float4*)(agg + (size_t)n * DIM))[c];
      vx = ((const float4*)(xin + (size_t)n * DIM))[c];
    }
    va.x *= s; va.y *= s; va.z *= s; va.w *= s;
    *(float4*)&sA[r * SR + c * 4] = va;
    *(float4*)&sX[r * SR + c * 4] = vx;
  }
  __syncthreads();

  const int jg = tid & 15, j0 = jg * 8;
  const int nr = tid >> 4;          // 0..15, each handles nodes nr*4 .. nr*4+3
  float acc[4][8];
#pragma unroll
  for (int jj = 0; jj < 8; ++jj) {
    float bv = b_l[j0 + jj];
    acc[0][jj] = bv; acc[1][jj] = bv; acc[2][jj] = bv; acc[3][jj] = bv;
  }

  for (int k = 0; k < DIM; ++k) {
    float wl[8], wr[8];
    *(float4*)&wl[0] = *(const float4*)(w_l + k * DIM + j0);
    *(float4*)&wl[4] = *(const float4*)(w_l + k * DIM + j0 + 4);
    *(float4*)&wr[0] = *(const float4*)(w_r + k * DIM + j0);
    *(float4*)&wr[4] = *(const float4*)(w_r + k * DIM + j0 + 4);
#pragma unroll
    for (int i = 0; i < 4; ++i) {
      float a  = sA[(nr * 4 + i) * SR + k];
      float xx = sX[(nr * 4 + i) * SR + k];
#pragma unroll
      for (int jj = 0; jj < 8; ++jj)
        acc[i][jj] = fmaf(a, wl[jj], fmaf(xx, wr[jj], acc[i][jj]));
    }
  }

#pragma unroll
  for (int i = 0; i < 4; ++i) {
    int n = base + nr * 4 + i;
    if (n < N_NODES) {
      float o[8];
#pragma unroll
      for (int jj = 0; jj < 8; ++jj) o[jj] = fmaxf(acc[i][jj], 0.f);
      *(float4*)(hout + (size_t)n * DIM + j0)     = *(float4*)&o[0];
      *(float4*)(hout + (size_t)n * DIM + j0 + 4) = *(float4*)&o[4];
    }
  }
}

// ---------------- fused final layer: out = sigmoid(relu(sage1) @ w_out + b_out) ----------------
__global__ __launch_bounds__(256) void k_sage_out(const float* __restrict__ agg,
                                                  const float* __restrict__ xin,
                                                  const float* __restrict__ invdeg,
                                                  const float* __restrict__ w_l,
                                                  const float* __restrict__ b_l,
                                                  const float* __restrict__ w_r,
                                                  const float* __restrict__ w_out,
                                                  const float* __restrict__ b_out,
                                                  float* __restrict__ out) {
  __shared__ float sA[NPB * SR];
  __shared__ float sX[NPB * SR];
  const int tid = threadIdx.x;
  const int base = blockIdx.x * NPB;

  for (int t = tid; t < NPB * 32; t += 256) {
    int r = t >> 5, c = t & 31;
    int n = base + r;
    float4 va = make_float4(0.f, 0.f, 0.f, 0.f);
    float4 vx = va;
    float s = 0.f;
    if (n < N_NODES) {
      s = invdeg[n];
      va = ((const float4*)(agg + (size_t)n * DIM))[c];
      vx = ((const float4*)(xin + (size_t)n * DIM))[c];
    }
    va.x *= s; va.y *= s; va.z *= s; va.w *= s;
    *(float4*)&sA[r * SR + c * 4] = va;
    *(float4*)&sX[r * SR + c * 4] = vx;
  }
  __syncthreads();

  const int jg = tid & 15, j0 = jg * 8;
  const int nr = tid >> 4;
  float acc[4][8];
#pragma unroll
  for (int jj = 0; jj < 8; ++jj) {
    float bv = b_l[j0 + jj];
    acc[0][jj] = bv; acc[1][jj] = bv; acc[2][jj] = bv; acc[3][jj] = bv;
  }

  for (int k = 0; k < DIM; ++k) {
    float wl[8], wr[8];
    *(float4*)&wl[0] = *(const float4*)(w_l + k * DIM + j0);
    *(float4*)&wl[4] = *(const float4*)(w_l + k * DIM + j0 + 4);
    *(float4*)&wr[0] = *(const float4*)(w_r + k * DIM + j0);
    *(float4*)&wr[4] = *(const float4*)(w_r + k * DIM + j0 + 4);
#pragma unroll
    for (int i = 0; i < 4; ++i) {
      float a  = sA[(nr * 4 + i) * SR + k];
      float xx = sX[(nr * 4 + i) * SR + k];
#pragma unroll
      for (int jj = 0; jj < 8; ++jj)
        acc[i][jj] = fmaf(a, wl[jj], fmaf(xx, wr[jj], acc[i][jj]));
    }
  }

  __syncthreads();   // done reading sA/sX; reuse sA as h1 tile
#pragma unroll
  for (int i = 0; i < 4; ++i)
#pragma unroll
    for (int jj = 0; jj < 8; ++jj)
      sA[(nr * 4 + i) * SR + j0 + jj] = fmaxf(acc[i][jj], 0.f);
  __syncthreads();

  // phase 2: out[64 nodes x 64 feats] = sigmoid(h1 @ w_out + b_out)
  const int og = tid & 7, jo = og * 8;
  const int nr2 = tid >> 3;          // 0..31, handles nodes nr2 and nr2+32
  float a2[2][8];
#pragma unroll
  for (int jj = 0; jj < 8; ++jj) {
    float bv = b_out[jo + jj];
    a2[0][jj] = bv; a2[1][jj] = bv;
  }
  for (int k = 0; k < DIM; ++k) {
    float wo[8];
    *(float4*)&wo[0] = *(const float4*)(w_out + k * ODIM + jo);
    *(float4*)&wo[4] = *(const float4*)(w_out + k * ODIM + jo + 4);
    float h0v = sA[nr2 * SR + k];
    float h1v = sA[(nr2 + 32) * SR + k];
#pragma unroll
    for (int jj = 0; jj < 8; ++jj) {
      a2[0][jj] = fmaf(h0v, wo[jj], a2[0][jj]);
      a2[1][jj] = fmaf(h1v, wo[jj], a2[1][jj]);
    }
  }
#pragma unroll
  for (int i = 0; i < 2; ++i) {
    int n = base + nr2 + 32 * i;
    if (n < N_NODES) {
      float o[8];
#pragma unroll
      for (int jj = 0; jj < 8; ++jj) o[jj] = 1.f / (1.f + __expf(-a2[i][jj]));
      *(float4*)(out + (size_t)n * ODIM + jo)     = *(float4*)&o[0];
      *(float4*)(out + (size_t)n * ODIM + jo + 4) = *(float4*)&o[4];
    }
  }
}

extern "C" void kernel_launch(void* const* d_in, const int* in_sizes, int n_in,
                              void* d_out, int out_size, void* d_ws, size_t ws_size,
                              hipStream_t stream) {
  const float* x     = (const float*)d_in[0];
  const int*   ei    = (const int*)d_in[1];
  const float* w_l0  = (const float*)d_in[2];
  const float* b_l0  = (const float*)d_in[3];
  const float* w_r0  = (const float*)d_in[4];
  const float* w_l1  = (const float*)d_in[5];
  const float* b_l1  = (const float*)d_in[6];
  const float* w_r1  = (const float*)d_in[7];
  const float* w_out = (const float*)d_in[8];
  const float* b_out = (const float*)d_in[9];
  float* out = (float*)d_out;

  const int* src = ei;
  const int* dst = ei + N_EDGES;

  char* ws = (char*)d_ws;
  float* deg = (float*)ws;                                     // 400 KB
  float* agg = (float*)(ws + (1ull << 20));                    // 51.2 MB
  float* h0  = (float*)(ws + (1ull << 20) + 51200000ull);      // 51.2 MB

  const size_t aggBytes = (size_t)N_NODES * DIM * sizeof(float);

  hipMemsetAsync(deg, 0, N_NODES * sizeof(float), stream);
  hipMemsetAsync(agg, 0, aggBytes, stream);

  k_deg<<<(N_EDGES + 255) / 256, 256, 0, stream>>>(dst, deg);
  k_invdeg<<<(N_NODES + 255) / 256, 256, 0, stream>>>(deg);

  k_scatter<<<(int)(((long long)N_EDGES * 32) / 256), 256, 0, stream>>>(x, src, dst, agg);

  int gblocks = (N_NODES + NPB - 1) / NPB;
  k_sage<<<gblocks, 256, 0, stream>>>(agg, x, deg, w_l0, b_l0, w_r0, h0);

  hipMemsetAsync(agg, 0, aggBytes, stream);
  k_scatter<<<(int)(((long long)N_EDGES * 32) / 256), 256, 0, stream>>>(h0, src, dst, agg);

  k_sage_out<<<gblocks, 256, 0, stream>>>(agg, h0, deg, w_l1, b_l1, w_r1, w_out, b_out, out);
}

// Round 2
// 832.699 us; speedup vs baseline: 6.9629x; 6.9629x over previous
//
#include <hip/hip_runtime.h>
#include <hip/hip_bf16.h>
#include <cstdint>

#define N_NODES 100000
#define N_EDGES 1600000
#define DIM 128
#define ODIM 64
#define NPB 64          // nodes per block in GEMM kernels
#define SR 132          // padded LDS row stride (floats)
#define SCAN_CHUNK 1024
#define NSCAN ((N_NODES + SCAN_CHUNK - 1) / SCAN_CHUNK)   // 98

typedef __hip_bfloat16 bf16;

// ---------------- CSR build ----------------
__global__ __launch_bounds__(256) void k_hist(const int* __restrict__ dst,
                                              int* __restrict__ cnt) {
  int e = blockIdx.x * 256 + threadIdx.x;
  if (e < N_EDGES) atomicAdd(&cnt[dst[e]], 1);
}

// per-chunk exclusive scan (in place over counts), chunk totals -> aux
__global__ __launch_bounds__(256) void k_scan1(int* __restrict__ rowptr,
                                               int* __restrict__ aux) {
  __shared__ int sums[256];
  const int b = blockIdx.x, t = threadIdx.x;
  const int idx = b * SCAN_CHUNK + t * 4;
  int4 v = make_int4(0, 0, 0, 0);
  if (idx + 3 < N_NODES) {
    v = *(const int4*)(rowptr + idx);
  } else {
    if (idx     < N_NODES) v.x = rowptr[idx];
    if (idx + 1 < N_NODES) v.y = rowptr[idx + 1];
    if (idx + 2 < N_NODES) v.z = rowptr[idx + 2];
    if (idx + 3 < N_NODES) v.w = rowptr[idx + 3];
  }
  int s = v.x + v.y + v.z + v.w;
  sums[t] = s;
  __syncthreads();
  for (int off = 1; off < 256; off <<= 1) {
    int val = (t >= off) ? sums[t - off] : 0;
    __syncthreads();
    sums[t] += val;
    __syncthreads();
  }
  int p = sums[t] - s;               // exclusive prefix of this thread
  if (t == 255) aux[b] = sums[255];  // chunk total
  if (idx     < N_NODES) rowptr[idx]     = p; p += v.x;
  if (idx + 1 < N_NODES) rowptr[idx + 1] = p; p += v.y;
  if (idx + 2 < N_NODES) rowptr[idx + 2] = p; p += v.z;
  if (idx + 3 < N_NODES) rowptr[idx + 3] = p;
}

__global__ __launch_bounds__(128) void k_scan2(int* __restrict__ aux) {
  __shared__ int sm[128];
  const int t = threadIdx.x;
  int v = (t < NSCAN) ? aux[t] : 0;
  sm[t] = v;
  __syncthreads();
  for (int off = 1; off < 128; off <<= 1) {
    int val = (t >= off) ? sm[t - off] : 0;
    __syncthreads();
    sm[t] += val;
    __syncthreads();
  }
  if (t < NSCAN) aux[t] = sm[t] - v;   // exclusive
}

__global__ __launch_bounds__(256) void k_scan3(int* __restrict__ rowptr,
                                               const int* __restrict__ aux,
                                               int* __restrict__ cursor) {
  int i = blockIdx.x * 256 + threadIdx.x;
  if (i < N_NODES) {
    int v = rowptr[i] + aux[i / SCAN_CHUNK];
    rowptr[i] = v;
    cursor[i] = v;
  }
  if (i == 0) rowptr[N_NODES] = N_EDGES;
}

__global__ __launch_bounds__(256) void k_fill(const int* __restrict__ src,
                                              const int* __restrict__ dst,
                                              int* __restrict__ cursor,
                                              int* __restrict__ col) {
  int e = blockIdx.x * 256 + threadIdx.x;
  if (e < N_EDGES) {
    int pos = atomicAdd(&cursor[dst[e]], 1);
    col[pos] = src[e];
  }
}

// ---------------- pull aggregation: agg[n] = mean_{e:dst=n} feat[src[e]]  (bf16 out) ----------------
__global__ __launch_bounds__(256) void k_agg(const float* __restrict__ feat,
                                             const int* __restrict__ rowptr,
                                             const int* __restrict__ col,
                                             bf16* __restrict__ agg) {
  int gid = blockIdx.x * 256 + threadIdx.x;
  int node = gid >> 6;
  int lane = gid & 63;
  if (node >= N_NODES) return;
  int beg = rowptr[node], end = rowptr[node + 1];
  float2 acc = make_float2(0.f, 0.f);
  for (int j = beg; j < end; ++j) {
    int s = col[j];
    float2 v = ((const float2*)(feat + (size_t)s * DIM))[lane];
    acc.x += v.x;
    acc.y += v.y;
  }
  float inv = (end > beg) ? 1.0f / (float)(end - beg) : 0.f;
  __hip_bfloat162 o;
  o.x = __float2bfloat16(acc.x * inv);
  o.y = __float2bfloat16(acc.y * inv);
  ((__hip_bfloat162*)(agg + (size_t)node * DIM))[lane] = o;
}

// ---------------- helpers ----------------
__device__ __forceinline__ void bf16x8_to_f32(const float4 raw, float* out) {
  union { float4 f4; uint32_t u[4]; } U;
  U.f4 = raw;
#pragma unroll
  for (int q = 0; q < 4; ++q) {
    uint32_t w = U.u[q];
    out[2 * q]     = __uint_as_float((w & 0xFFFFu) << 16);
    out[2 * q + 1] = __uint_as_float(w & 0xFFFF0000u);
  }
}

// ---------------- fused SAGE layer: h = relu(agg @ w_l + b + x @ w_r) ----------------
__global__ __launch_bounds__(256) void k_sage(const bf16* __restrict__ agg,
                                              const float* __restrict__ xin,
                                              const float* __restrict__ w_l,
                                              const float* __restrict__ b_l,
                                              const float* __restrict__ w_r,
                                              float* __restrict__ hout) {
  __shared__ float sA[NPB * SR];
  __shared__ float sX[NPB * SR];
  const int tid = threadIdx.x;
  const int base = blockIdx.x * NPB;

  // stage agg (bf16 -> f32)
  for (int t = tid; t < NPB * 16; t += 256) {
    int r = t >> 4, c = t & 15;
    int n = base + r;
    float4 raw = make_float4(0.f, 0.f, 0.f, 0.f);
    if (n < N_NODES) raw = ((const float4*)(agg + (size_t)n * DIM))[c];
    float vals[8];
    bf16x8_to_f32(raw, vals);
    *(float4*)&sA[r * SR + c * 8]     = *(float4*)&vals[0];
    *(float4*)&sA[r * SR + c * 8 + 4] = *(float4*)&vals[4];
  }
  // stage x (f32)
  for (int t = tid; t < NPB * 32; t += 256) {
    int r = t >> 5, c = t & 31;
    int n = base + r;
    float4 vx = make_float4(0.f, 0.f, 0.f, 0.f);
    if (n < N_NODES) vx = ((const float4*)(xin + (size_t)n * DIM))[c];
    *(float4*)&sX[r * SR + c * 4] = vx;
  }
  __syncthreads();

  const int jg = tid & 15, j0 = jg * 8;
  const int nr = tid >> 4;
  float acc[4][8];
#pragma unroll
  for (int jj = 0; jj < 8; ++jj) {
    float bv = b_l[j0 + jj];
    acc[0][jj] = bv; acc[1][jj] = bv; acc[2][jj] = bv; acc[3][jj] = bv;
  }

  for (int k = 0; k < DIM; ++k) {
    float wl[8], wr[8];
    *(float4*)&wl[0] = *(const float4*)(w_l + k * DIM + j0);
    *(float4*)&wl[4] = *(const float4*)(w_l + k * DIM + j0 + 4);
    *(float4*)&wr[0] = *(const float4*)(w_r + k * DIM + j0);
    *(float4*)&wr[4] = *(const float4*)(w_r + k * DIM + j0 + 4);
#pragma unroll
    for (int i = 0; i < 4; ++i) {
      float a  = sA[(nr * 4 + i) * SR + k];
      float xx = sX[(nr * 4 + i) * SR + k];
#pragma unroll
      for (int jj = 0; jj < 8; ++jj)
        acc[i][jj] = fmaf(a, wl[jj], fmaf(xx, wr[jj], acc[i][jj]));
    }
  }

#pragma unroll
  for (int i = 0; i < 4; ++i) {
    int n = base + nr * 4 + i;
    if (n < N_NODES) {
      float o[8];
#pragma unroll
      for (int jj = 0; jj < 8; ++jj) o[jj] = fmaxf(acc[i][jj], 0.f);
      *(float4*)(hout + (size_t)n * DIM + j0)     = *(float4*)&o[0];
      *(float4*)(hout + (size_t)n * DIM + j0 + 4) = *(float4*)&o[4];
    }
  }
}

// ---------------- fused final layer: out = sigmoid(relu(sage1) @ w_out + b_out) ----------------
__global__ __launch_bounds__(256) void k_sage_out(const bf16* __restrict__ agg,
                                                  const float* __restrict__ xin,
                                                  const float* __restrict__ w_l,
                                                  const float* __restrict__ b_l,
                                                  const float* __restrict__ w_r,
                                                  const float* __restrict__ w_out,
                                                  const float* __restrict__ b_out,
                                                  float* __restrict__ out) {
  __shared__ float sA[NPB * SR];
  __shared__ float sX[NPB * SR];
  const int tid = threadIdx.x;
  const int base = blockIdx.x * NPB;

  for (int t = tid; t < NPB * 16; t += 256) {
    int r = t >> 4, c = t & 15;
    int n = base + r;
    float4 raw = make_float4(0.f, 0.f, 0.f, 0.f);
    if (n < N_NODES) raw = ((const float4*)(agg + (size_t)n * DIM))[c];
    float vals[8];
    bf16x8_to_f32(raw, vals);
    *(float4*)&sA[r * SR + c * 8]     = *(float4*)&vals[0];
    *(float4*)&sA[r * SR + c * 8 + 4] = *(float4*)&vals[4];
  }
  for (int t = tid; t < NPB * 32; t += 256) {
    int r = t >> 5, c = t & 31;
    int n = base + r;
    float4 vx = make_float4(0.f, 0.f, 0.f, 0.f);
    if (n < N_NODES) vx = ((const float4*)(xin + (size_t)n * DIM))[c];
    *(float4*)&sX[r * SR + c * 4] = vx;
  }
  __syncthreads();

  const int jg = tid & 15, j0 = jg * 8;
  const int nr = tid >> 4;
  float acc[4][8];
#pragma unroll
  for (int jj = 0; jj < 8; ++jj) {
    float bv = b_l[j0 + jj];
    acc[0][jj] = bv; acc[1][jj] = bv; acc[2][jj] = bv; acc[3][jj] = bv;
  }

  for (int k = 0; k < DIM; ++k) {
    float wl[8], wr[8];
    *(float4*)&wl[0] = *(const float4*)(w_l + k * DIM + j0);
    *(float4*)&wl[4] = *(const float4*)(w_l + k * DIM + j0 + 4);
    *(float4*)&wr[0] = *(const float4*)(w_r + k * DIM + j0);
    *(float4*)&wr[4] = *(const float4*)(w_r + k * DIM + j0 + 4);
#pragma unroll
    for (int i = 0; i < 4; ++i) {
      float a  = sA[(nr * 4 + i) * SR + k];
      float xx = sX[(nr * 4 + i) * SR + k];
#pragma unroll
      for (int jj = 0; jj < 8; ++jj)
        acc[i][jj] = fmaf(a, wl[jj], fmaf(xx, wr[jj], acc[i][jj]));
    }
  }

  __syncthreads();   // done reading sA/sX; reuse sA as h1 tile
#pragma unroll
  for (int i = 0; i < 4; ++i)
#pragma unroll
    for (int jj = 0; jj < 8; ++jj)
      sA[(nr * 4 + i) * SR + j0 + jj] = fmaxf(acc[i][jj], 0.f);
  __syncthreads();

  const int og = tid & 7, jo = og * 8;
  const int nr2 = tid >> 3;
  float a2[2][8];
#pragma unroll
  for (int jj = 0; jj < 8; ++jj) {
    float bv = b_out[jo + jj];
    a2[0][jj] = bv; a2[1][jj] = bv;
  }
  for (int k = 0; k < DIM; ++k) {
    float wo[8];
    *(float4*)&wo[0] = *(const float4*)(w_out + k * ODIM + jo);
    *(float4*)&wo[4] = *(const float4*)(w_out + k * ODIM + jo + 4);
    float h0v = sA[nr2 * SR + k];
    float h1v = sA[(nr2 + 32) * SR + k];
#pragma unroll
    for (int jj = 0; jj < 8; ++jj) {
      a2[0][jj] = fmaf(h0v, wo[jj], a2[0][jj]);
      a2[1][jj] = fmaf(h1v, wo[jj], a2[1][jj]);
    }
  }
#pragma unroll
  for (int i = 0; i < 2; ++i) {
    int n = base + nr2 + 32 * i;
    if (n < N_NODES) {
      float o[8];
#pragma unroll
      for (int jj = 0; jj < 8; ++jj) o[jj] = 1.f / (1.f + __expf(-a2[i][jj]));
      *(float4*)(out + (size_t)n * ODIM + jo)     = *(float4*)&o[0];
      *(float4*)(out + (size_t)n * ODIM + jo + 4) = *(float4*)&o[4];
    }
  }
}

extern "C" void kernel_launch(void* const* d_in, const int* in_sizes, int n_in,
                              void* d_out, int out_size, void* d_ws, size_t ws_size,
                              hipStream_t stream) {
  const float* x     = (const float*)d_in[0];
  const int*   ei    = (const int*)d_in[1];
  const float* w_l0  = (const float*)d_in[2];
  const float* b_l0  = (const float*)d_in[3];
  const float* w_r0  = (const float*)d_in[4];
  const float* w_l1  = (const float*)d_in[5];
  const float* b_l1  = (const float*)d_in[6];
  const float* w_r1  = (const float*)d_in[7];
  const float* w_out = (const float*)d_in[8];
  const float* b_out = (const float*)d_in[9];
  float* out = (float*)d_out;

  const int* src = ei;
  const int* dst = ei + N_EDGES;

  char* ws = (char*)d_ws;
  int*  rowptr = (int*)(ws);                       // 400,004 B
  int*  cursor = (int*)(ws + (512u << 10));        // 400 KB
  int*  aux    = (int*)(ws + (1u << 20));          // ~1 KB
  int*  col    = (int*)(ws + (2u << 20));          // 6.4 MB
  bf16* aggb   = (bf16*)(ws + (9u << 20));         // 25.6 MB
  float* h0    = (float*)(ws + (35ull << 20));     // 51.2 MB  (total ~86.2 MB)

  // --- CSR build (reused by both layers) ---
  hipMemsetAsync(rowptr, 0, (N_NODES + 1) * sizeof(int), stream);
  k_hist <<<(N_EDGES + 255) / 256, 256, 0, stream>>>(dst, rowptr);
  k_scan1<<<NSCAN, 256, 0, stream>>>(rowptr, aux);
  k_scan2<<<1, 128, 0, stream>>>(aux);
  k_scan3<<<(N_NODES + 255) / 256, 256, 0, stream>>>(rowptr, aux, cursor);
  k_fill <<<(N_EDGES + 255) / 256, 256, 0, stream>>>(src, dst, cursor, col);

  const int ablocks = (N_NODES * 64 + 255) / 256;
  const int gblocks = (N_NODES + NPB - 1) / NPB;

  // --- layer 0 ---
  k_agg <<<ablocks, 256, 0, stream>>>(x, rowptr, col, aggb);
  k_sage<<<gblocks, 256, 0, stream>>>(aggb, x, w_l0, b_l0, w_r0, h0);

  // --- layer 1 + output head ---
  k_agg <<<ablocks, 256, 0, stream>>>(h0, rowptr, col, aggb);
  k_sage_out<<<gblocks, 256, 0, stream>>>(aggb, h0, w_l1, b_l1, w_r1, w_out, b_out, out);
}

// Round 3
// 579.818 us; speedup vs baseline: 9.9998x; 1.4361x over previous
//
#include <hip/hip_runtime.h>
#include <hip/hip_bf16.h>
#include <cstdint>

#define N_NODES 100000
#define N_EDGES 1600000
#define DIM 128
#define K2 256
#define ODIM 64
#define NPB 64
#define SCAN_CHUNK 1024
#define NSCAN ((N_NODES + SCAN_CHUNK - 1) / SCAN_CHUNK)   // 98

typedef __hip_bfloat16 bf16;
typedef __attribute__((ext_vector_type(8))) short bfrag;   // 8 bf16 = 4 VGPRs
typedef __attribute__((ext_vector_type(4))) float f32x4;

// ---------------- CSR build ----------------
__global__ __launch_bounds__(256) void k_hist(const int* __restrict__ dst,
                                              int* __restrict__ cnt) {
  int e = blockIdx.x * 256 + threadIdx.x;
  if (e < N_EDGES) atomicAdd(&cnt[dst[e]], 1);
}

__global__ __launch_bounds__(256) void k_scan1(int* __restrict__ rowptr,
                                               int* __restrict__ aux) {
  __shared__ int sums[256];
  const int b = blockIdx.x, t = threadIdx.x;
  const int idx = b * SCAN_CHUNK + t * 4;
  int4 v = make_int4(0, 0, 0, 0);
  if (idx + 3 < N_NODES) {
    v = *(const int4*)(rowptr + idx);
  } else {
    if (idx     < N_NODES) v.x = rowptr[idx];
    if (idx + 1 < N_NODES) v.y = rowptr[idx + 1];
    if (idx + 2 < N_NODES) v.z = rowptr[idx + 2];
    if (idx + 3 < N_NODES) v.w = rowptr[idx + 3];
  }
  int s = v.x + v.y + v.z + v.w;
  sums[t] = s;
  __syncthreads();
  for (int off = 1; off < 256; off <<= 1) {
    int val = (t >= off) ? sums[t - off] : 0;
    __syncthreads();
    sums[t] += val;
    __syncthreads();
  }
  int p = sums[t] - s;
  if (t == 255) aux[b] = sums[255];
  if (idx     < N_NODES) rowptr[idx]     = p; p += v.x;
  if (idx + 1 < N_NODES) rowptr[idx + 1] = p; p += v.y;
  if (idx + 2 < N_NODES) rowptr[idx + 2] = p; p += v.z;
  if (idx + 3 < N_NODES) rowptr[idx + 3] = p;
}

__global__ __launch_bounds__(128) void k_scan2(int* __restrict__ aux) {
  __shared__ int sm[128];
  const int t = threadIdx.x;
  int v = (t < NSCAN) ? aux[t] : 0;
  sm[t] = v;
  __syncthreads();
  for (int off = 1; off < 128; off <<= 1) {
    int val = (t >= off) ? sm[t - off] : 0;
    __syncthreads();
    sm[t] += val;
    __syncthreads();
  }
  if (t < NSCAN) aux[t] = sm[t] - v;
}

__global__ __launch_bounds__(256) void k_scan3(int* __restrict__ rowptr,
                                               const int* __restrict__ aux,
                                               int* __restrict__ cursor) {
  int i = blockIdx.x * 256 + threadIdx.x;
  if (i < N_NODES) {
    int v = rowptr[i] + aux[i / SCAN_CHUNK];
    rowptr[i] = v;
    cursor[i] = v;
  }
  if (i == 0) rowptr[N_NODES] = N_EDGES;
}

__global__ __launch_bounds__(256) void k_fill(const int* __restrict__ src,
                                              const int* __restrict__ dst,
                                              int* __restrict__ cursor,
                                              int* __restrict__ col) {
  int e = blockIdx.x * 256 + threadIdx.x;
  if (e < N_EDGES) {
    int pos = atomicAdd(&cursor[dst[e]], 1);
    col[pos] = src[e];
  }
}

// ---------------- precompute: x -> bf16 ----------------
__global__ __launch_bounds__(256) void k_cvt(const float* __restrict__ x,
                                             bf16* __restrict__ xb) {
  int i = (blockIdx.x * 256 + threadIdx.x) * 4;
  if (i >= N_NODES * DIM) return;
  float4 v = *(const float4*)(x + i);
  bf16 t[4];
  t[0] = __float2bfloat16(v.x);
  t[1] = __float2bfloat16(v.y);
  t[2] = __float2bfloat16(v.z);
  t[3] = __float2bfloat16(v.w);
  *(uint2*)(xb + i) = *(uint2*)t;
}

// ---------------- precompute: pack weights transposed bf16 ----------------
// WT[j][k] (j<128, k<256): k<128 -> w_l[k][j], else w_r[k-128][j].  WoT[j][k] = w_out[k][j].
__global__ __launch_bounds__(256) void k_prepw(const float* __restrict__ wl0,
                                               const float* __restrict__ wr0,
                                               const float* __restrict__ wl1,
                                               const float* __restrict__ wr1,
                                               const float* __restrict__ wo,
                                               bf16* __restrict__ WT0,
                                               bf16* __restrict__ WT1,
                                               bf16* __restrict__ WoT) {
  int g = blockIdx.x * 256 + threadIdx.x;
  if (g < 32768) {
    int j = g >> 8, k = g & 255;
    float v = (k < DIM) ? wl0[k * DIM + j] : wr0[(k - DIM) * DIM + j];
    WT0[g] = __float2bfloat16(v);
  } else if (g < 65536) {
    int gg = g - 32768;
    int j = gg >> 8, k = gg & 255;
    float v = (k < DIM) ? wl1[k * DIM + j] : wr1[(k - DIM) * DIM + j];
    WT1[gg] = __float2bfloat16(v);
  } else if (g < 65536 + 8192) {
    int gg = g - 65536;
    int j = gg >> 7, k = gg & 127;
    WoT[gg] = __float2bfloat16(wo[k * ODIM + j]);
  }
}

// ---------------- pull aggregation (bf16 in, bf16 out) ----------------
__global__ __launch_bounds__(256) void k_agg(const bf16* __restrict__ feat,
                                             const int* __restrict__ rowptr,
                                             const int* __restrict__ col,
                                             bf16* __restrict__ agg) {
  int gid = blockIdx.x * 256 + threadIdx.x;
  int node = gid >> 6;
  int lane = gid & 63;
  if (node >= N_NODES) return;
  int beg = rowptr[node], end = rowptr[node + 1];
  float ax = 0.f, ay = 0.f;
  const uint32_t* fp = (const uint32_t*)feat;
  for (int j = beg; j < end; ++j) {
    int s = col[j];
    uint32_t v = fp[(size_t)s * (DIM / 2) + lane];
    ax += __uint_as_float((v & 0xFFFFu) << 16);
    ay += __uint_as_float(v & 0xFFFF0000u);
  }
  float inv = (end > beg) ? 1.0f / (float)(end - beg) : 0.f;
  __hip_bfloat162 o;
  o.x = __float2bfloat16(ax * inv);
  o.y = __float2bfloat16(ay * inv);
  ((__hip_bfloat162*)(agg + (size_t)node * DIM))[lane] = o;
}

// ---------------- MFMA SAGE layer: h = relu([agg|x] @ WT^T + b) ----------------
// A-tile 64x256 bf16 in LDS, XOR-swizzled (T2): byte ^= (row&7)<<4.
__global__ __launch_bounds__(256) void k_sage(const bf16* __restrict__ agg,
                                              const bf16* __restrict__ xb,
                                              const bf16* __restrict__ WT,
                                              const float* __restrict__ bias,
                                              bf16* __restrict__ hout) {
  __shared__ char sA[NPB * 512];   // 32 KB
  const int tid = threadIdx.x;
  const int base = blockIdx.x * NPB;

#pragma unroll
  for (int i = 0; i < 8; ++i) {
    int c = tid + 256 * i;                  // chunk 0..2047 (16B each)
    int row = c >> 5, kc = c & 31;
    int n = base + row;
    uint4 v = make_uint4(0, 0, 0, 0);
    if (n < N_NODES) {
      const bf16* sp = (kc < 16) ? (agg + (size_t)n * DIM + kc * 8)
                                 : (xb + (size_t)n * DIM + (kc - 16) * 8);
      v = *(const uint4*)sp;
    }
    int byte = (row * 512 + kc * 16) ^ ((row & 7) << 4);
    *(uint4*)(sA + byte) = v;
  }
  __syncthreads();

  const int w = tid >> 6, lane = tid & 63;
  const int j0 = w * 32;
  const int lrow = lane & 15, lk = lane >> 4;

  f32x4 acc[4][2];
#pragma unroll
  for (int mi = 0; mi < 4; ++mi)
#pragma unroll
    for (int ni = 0; ni < 2; ++ni)
      acc[mi][ni] = (f32x4){0.f, 0.f, 0.f, 0.f};

  for (int kt = 0; kt < 8; ++kt) {
    bfrag b0 = *(const bfrag*)(WT + (size_t)(j0 + lrow) * K2 + kt * 32 + lk * 8);
    bfrag b1 = *(const bfrag*)(WT + (size_t)(j0 + 16 + lrow) * K2 + kt * 32 + lk * 8);
#pragma unroll
    for (int mi = 0; mi < 4; ++mi) {
      int row = mi * 16 + lrow;
      int byte = (row * 512 + kt * 64 + lk * 16) ^ ((row & 7) << 4);
      bfrag a = *(const bfrag*)(sA + byte);
      acc[mi][0] = __builtin_amdgcn_mfma_f32_16x16x32_bf16(a, b0, acc[mi][0], 0, 0, 0);
      acc[mi][1] = __builtin_amdgcn_mfma_f32_16x16x32_bf16(a, b1, acc[mi][1], 0, 0, 0);
    }
  }

#pragma unroll
  for (int ni = 0; ni < 2; ++ni) {
    int colj = j0 + ni * 16 + lrow;
    float bv = bias[colj];
#pragma unroll
    for (int mi = 0; mi < 4; ++mi) {
#pragma unroll
      for (int r = 0; r < 4; ++r) {
        int n = base + mi * 16 + lk * 4 + r;
        if (n < N_NODES)
          hout[(size_t)n * DIM + colj] = __float2bfloat16(fmaxf(acc[mi][ni][r] + bv, 0.f));
      }
    }
  }
}

// ---------------- MFMA layer 1 + head: out = sigmoid(relu([agg|h0]@WT1^T+b1) @ WoT^T + bo) ----------------
__global__ __launch_bounds__(256) void k_out(const bf16* __restrict__ agg,
                                             const bf16* __restrict__ xb,
                                             const bf16* __restrict__ WT,
                                             const float* __restrict__ bias,
                                             const bf16* __restrict__ WoT,
                                             const float* __restrict__ bo,
                                             float* __restrict__ out) {
  __shared__ char sA[NPB * 512];
  const int tid = threadIdx.x;
  const int base = blockIdx.x * NPB;

#pragma unroll
  for (int i = 0; i < 8; ++i) {
    int c = tid + 256 * i;
    int row = c >> 5, kc = c & 31;
    int n = base + row;
    uint4 v = make_uint4(0, 0, 0, 0);
    if (n < N_NODES) {
      const bf16* sp = (kc < 16) ? (agg + (size_t)n * DIM + kc * 8)
                                 : (xb + (size_t)n * DIM + (kc - 16) * 8);
      v = *(const uint4*)sp;
    }
    int byte = (row * 512 + kc * 16) ^ ((row & 7) << 4);
    *(uint4*)(sA + byte) = v;
  }
  __syncthreads();

  const int w = tid >> 6, lane = tid & 63;
  const int j0 = w * 32;
  const int lrow = lane & 15, lk = lane >> 4;

  f32x4 acc[4][2];
#pragma unroll
  for (int mi = 0; mi < 4; ++mi)
#pragma unroll
    for (int ni = 0; ni < 2; ++ni)
      acc[mi][ni] = (f32x4){0.f, 0.f, 0.f, 0.f};

  for (int kt = 0; kt < 8; ++kt) {
    bfrag b0 = *(const bfrag*)(WT + (size_t)(j0 + lrow) * K2 + kt * 32 + lk * 8);
    bfrag b1 = *(const bfrag*)(WT + (size_t)(j0 + 16 + lrow) * K2 + kt * 32 + lk * 8);
#pragma unroll
    for (int mi = 0; mi < 4; ++mi) {
      int row = mi * 16 + lrow;
      int byte = (row * 512 + kt * 64 + lk * 16) ^ ((row & 7) << 4);
      bfrag a = *(const bfrag*)(sA + byte);
      acc[mi][0] = __builtin_amdgcn_mfma_f32_16x16x32_bf16(a, b0, acc[mi][0], 0, 0, 0);
      acc[mi][1] = __builtin_amdgcn_mfma_f32_16x16x32_bf16(a, b1, acc[mi][1], 0, 0, 0);
    }
  }

  __syncthreads();   // everyone done reading sA; reuse as h1 tile [64][256B], swizzled
#pragma unroll
  for (int ni = 0; ni < 2; ++ni) {
    int colj = j0 + ni * 16 + lrow;
    float bv = bias[colj];
#pragma unroll
    for (int mi = 0; mi < 4; ++mi) {
#pragma unroll
      for (int r = 0; r < 4; ++r) {
        int row = mi * 16 + lk * 4 + r;
        float v = fmaxf(acc[mi][ni][r] + bv, 0.f);
        int byte = (row * 256 + colj * 2) ^ ((row & 7) << 4);
        *(bf16*)(sA + byte) = __float2bfloat16(v);
      }
    }
  }
  __syncthreads();

  // phase 2: out[64 x 64] = sigmoid(h1 @ WoT^T + bo); wave w -> cols w*16..w*16+15
  const int jo = w * 16;
  f32x4 acc2[4];
#pragma unroll
  for (int mi = 0; mi < 4; ++mi) acc2[mi] = (f32x4){0.f, 0.f, 0.f, 0.f};

#pragma unroll
  for (int kt = 0; kt < 4; ++kt) {
    bfrag b = *(const bfrag*)(WoT + (size_t)(jo + lrow) * DIM + kt * 32 + lk * 8);
#pragma unroll
    for (int mi = 0; mi < 4; ++mi) {
      int row = mi * 16 + lrow;
      int byte = (row * 256 + kt * 64 + lk * 16) ^ ((row & 7) << 4);
      bfrag a = *(const bfrag*)(sA + byte);
      acc2[mi] = __builtin_amdgcn_mfma_f32_16x16x32_bf16(a, b, acc2[mi], 0, 0, 0);
    }
  }

  int colj = jo + lrow;
  float bv = bo[colj];
#pragma unroll
  for (int mi = 0; mi < 4; ++mi) {
#pragma unroll
    for (int r = 0; r < 4; ++r) {
      int n = base + mi * 16 + lk * 4 + r;
      if (n < N_NODES)
        out[(size_t)n * ODIM + colj] = 1.f / (1.f + __expf(-(acc2[mi][r] + bv)));
    }
  }
}

extern "C" void kernel_launch(void* const* d_in, const int* in_sizes, int n_in,
                              void* d_out, int out_size, void* d_ws, size_t ws_size,
                              hipStream_t stream) {
  const float* x     = (const float*)d_in[0];
  const int*   ei    = (const int*)d_in[1];
  const float* w_l0  = (const float*)d_in[2];
  const float* b_l0  = (const float*)d_in[3];
  const float* w_r0  = (const float*)d_in[4];
  const float* w_l1  = (const float*)d_in[5];
  const float* b_l1  = (const float*)d_in[6];
  const float* w_r1  = (const float*)d_in[7];
  const float* w_out = (const float*)d_in[8];
  const float* b_out = (const float*)d_in[9];
  float* out = (float*)d_out;

  const int* src = ei;
  const int* dst = ei + N_EDGES;

  char* ws = (char*)d_ws;
  int*  rowptr = (int*)(ws);                        // 400,004 B
  int*  cursor = (int*)(ws + (512u << 10));
  int*  aux    = (int*)(ws + (1u << 20));
  int*  col    = (int*)(ws + (2u << 20));           // 6.4 MB
  bf16* WT0    = (bf16*)(ws + (9u << 20));          // 64 KB
  bf16* WT1    = (bf16*)(ws + (9u << 20) + 65536);  // 64 KB
  bf16* WoT    = (bf16*)(ws + (9u << 20) + 131072); // 16 KB
  bf16* aggb   = (bf16*)(ws + (10u << 20));         // 25.6 MB
  bf16* h0b    = (bf16*)(ws + (36ull << 20));       // 25.6 MB
  bf16* xb     = (bf16*)(ws + (62ull << 20));       // 25.6 MB (~88 MB total)

  // --- precompute (independent of CSR) ---
  k_cvt  <<<(N_NODES * DIM / 4 + 255) / 256, 256, 0, stream>>>(x, xb);
  k_prepw<<<(65536 + 8192 + 255) / 256, 256, 0, stream>>>(w_l0, w_r0, w_l1, w_r1, w_out,
                                                          WT0, WT1, WoT);

  // --- CSR build ---
  hipMemsetAsync(rowptr, 0, (N_NODES + 1) * sizeof(int), stream);
  k_hist <<<(N_EDGES + 255) / 256, 256, 0, stream>>>(dst, rowptr);
  k_scan1<<<NSCAN, 256, 0, stream>>>(rowptr, aux);
  k_scan2<<<1, 128, 0, stream>>>(aux);
  k_scan3<<<(N_NODES + 255) / 256, 256, 0, stream>>>(rowptr, aux, cursor);
  k_fill <<<(N_EDGES + 255) / 256, 256, 0, stream>>>(src, dst, cursor, col);

  const int ablocks = (N_NODES * 64 + 255) / 256;
  const int gblocks = (N_NODES + NPB - 1) / NPB;

  // --- layer 0 ---
  k_agg <<<ablocks, 256, 0, stream>>>(xb, rowptr, col, aggb);
  k_sage<<<gblocks, 256, 0, stream>>>(aggb, xb, WT0, b_l0, h0b);

  // --- layer 1 + head ---
  k_agg<<<ablocks, 256, 0, stream>>>(h0b, rowptr, col, aggb);
  k_out<<<gblocks, 256, 0, stream>>>(aggb, h0b, WT1, b_l1, WoT, b_out, out);
}

// Round 4
// 399.416 us; speedup vs baseline: 14.5163x; 1.4517x over previous
//
#include <hip/hip_runtime.h>
#include <hip/hip_bf16.h>
#include <cstdint>

#define N_NODES 100000
#define N_EDGES 1600000
#define DIM 128
#define K2 256
#define ODIM 64
#define NPB 64
#define SCAN_CHUNK 1024
#define NSCAN ((N_NODES + SCAN_CHUNK - 1) / SCAN_CHUNK)   // 98

typedef __hip_bfloat16 bf16;
typedef __attribute__((ext_vector_type(8))) short bfrag;   // 8 bf16 = 4 VGPRs
typedef __attribute__((ext_vector_type(4))) float f32x4;

// ---------------- CSR build ----------------
__global__ __launch_bounds__(256) void k_hist(const int* __restrict__ dst,
                                              int* __restrict__ cnt) {
  int e = blockIdx.x * 256 + threadIdx.x;
  if (e < N_EDGES) atomicAdd(&cnt[dst[e]], 1);
}

__global__ __launch_bounds__(256) void k_scan1(int* __restrict__ rowptr,
                                               int* __restrict__ aux) {
  __shared__ int sums[256];
  const int b = blockIdx.x, t = threadIdx.x;
  const int idx = b * SCAN_CHUNK + t * 4;
  int4 v = make_int4(0, 0, 0, 0);
  if (idx + 3 < N_NODES) {
    v = *(const int4*)(rowptr + idx);
  } else {
    if (idx     < N_NODES) v.x = rowptr[idx];
    if (idx + 1 < N_NODES) v.y = rowptr[idx + 1];
    if (idx + 2 < N_NODES) v.z = rowptr[idx + 2];
    if (idx + 3 < N_NODES) v.w = rowptr[idx + 3];
  }
  int s = v.x + v.y + v.z + v.w;
  sums[t] = s;
  __syncthreads();
  for (int off = 1; off < 256; off <<= 1) {
    int val = (t >= off) ? sums[t - off] : 0;
    __syncthreads();
    sums[t] += val;
    __syncthreads();
  }
  int p = sums[t] - s;
  if (t == 255) aux[b] = sums[255];
  if (idx     < N_NODES) rowptr[idx]     = p; p += v.x;
  if (idx + 1 < N_NODES) rowptr[idx + 1] = p; p += v.y;
  if (idx + 2 < N_NODES) rowptr[idx + 2] = p; p += v.z;
  if (idx + 3 < N_NODES) rowptr[idx + 3] = p;
}

__global__ __launch_bounds__(128) void k_scan2(int* __restrict__ aux) {
  __shared__ int sm[128];
  const int t = threadIdx.x;
  int v = (t < NSCAN) ? aux[t] : 0;
  sm[t] = v;
  __syncthreads();
  for (int off = 1; off < 128; off <<= 1) {
    int val = (t >= off) ? sm[t - off] : 0;
    __syncthreads();
    sm[t] += val;
    __syncthreads();
  }
  if (t < NSCAN) aux[t] = sm[t] - v;
}

__global__ __launch_bounds__(256) void k_scan3(int* __restrict__ rowptr,
                                               const int* __restrict__ aux,
                                               int* __restrict__ cursor) {
  int i = blockIdx.x * 256 + threadIdx.x;
  if (i < N_NODES) {
    int v = rowptr[i] + aux[i / SCAN_CHUNK];
    rowptr[i] = v;
    cursor[i] = v;
  }
  if (i == 0) rowptr[N_NODES] = N_EDGES;
}

__global__ __launch_bounds__(256) void k_fill(const int* __restrict__ src,
                                              const int* __restrict__ dst,
                                              int* __restrict__ cursor,
                                              int* __restrict__ col) {
  int e = blockIdx.x * 256 + threadIdx.x;
  if (e < N_EDGES) {
    int pos = atomicAdd(&cursor[dst[e]], 1);
    col[pos] = src[e];
  }
}

// ---------------- precompute: x -> bf16 ----------------
__global__ __launch_bounds__(256) void k_cvt(const float* __restrict__ x,
                                             bf16* __restrict__ xb) {
  int i = (blockIdx.x * 256 + threadIdx.x) * 4;
  if (i >= N_NODES * DIM) return;
  float4 v = *(const float4*)(x + i);
  bf16 t[4];
  t[0] = __float2bfloat16(v.x);
  t[1] = __float2bfloat16(v.y);
  t[2] = __float2bfloat16(v.z);
  t[3] = __float2bfloat16(v.w);
  *(uint2*)(xb + i) = *(uint2*)t;
}

// ---------------- precompute: pack weights transposed bf16 ----------------
__global__ __launch_bounds__(256) void k_prepw(const float* __restrict__ wl0,
                                               const float* __restrict__ wr0,
                                               const float* __restrict__ wl1,
                                               const float* __restrict__ wr1,
                                               const float* __restrict__ wo,
                                               bf16* __restrict__ WT0,
                                               bf16* __restrict__ WT1,
                                               bf16* __restrict__ WoT) {
  int g = blockIdx.x * 256 + threadIdx.x;
  if (g < 32768) {
    int j = g >> 8, k = g & 255;
    float v = (k < DIM) ? wl0[k * DIM + j] : wr0[(k - DIM) * DIM + j];
    WT0[g] = __float2bfloat16(v);
  } else if (g < 65536) {
    int gg = g - 32768;
    int j = gg >> 8, k = gg & 255;
    float v = (k < DIM) ? wl1[k * DIM + j] : wr1[(k - DIM) * DIM + j];
    WT1[gg] = __float2bfloat16(v);
  } else if (g < 65536 + 8192) {
    int gg = g - 65536;
    int j = gg >> 7, k = gg & 127;
    WoT[gg] = __float2bfloat16(wo[k * ODIM + j]);
  }
}

// ---------------- pull aggregation, 4 edges/wave in parallel + 2x unroll ----------------
__device__ __forceinline__ void acc8(float* acc, uint4 v) {
  acc[0] += __uint_as_float(v.x << 16);
  acc[1] += __uint_as_float(v.x & 0xFFFF0000u);
  acc[2] += __uint_as_float(v.y << 16);
  acc[3] += __uint_as_float(v.y & 0xFFFF0000u);
  acc[4] += __uint_as_float(v.z << 16);
  acc[5] += __uint_as_float(v.z & 0xFFFF0000u);
  acc[6] += __uint_as_float(v.w << 16);
  acc[7] += __uint_as_float(v.w & 0xFFFF0000u);
}

__global__ __launch_bounds__(256) void k_agg(const bf16* __restrict__ feat,
                                             const int* __restrict__ rowptr,
                                             const int* __restrict__ col,
                                             bf16* __restrict__ agg) {
  int gid = blockIdx.x * 256 + threadIdx.x;
  int node = gid >> 6;
  if (node >= N_NODES) return;
  int lane = gid & 63;
  int g = lane >> 4, lg = lane & 15;          // group 0..3 = edge slot, lane-in-group = 16B chunk
  int beg = rowptr[node], end = rowptr[node + 1];

  float acc[8];
#pragma unroll
  for (int q = 0; q < 8; ++q) acc[q] = 0.f;

  int j = beg;
  // 8 edges in flight (2 x 4-edge groups)
  for (; j + 8 <= end; j += 8) {
    int s0 = col[j + g];
    int s1 = col[j + 4 + g];
    uint4 v0 = *(const uint4*)(feat + (size_t)s0 * DIM + lg * 8);
    uint4 v1 = *(const uint4*)(feat + (size_t)s1 * DIM + lg * 8);
    acc8(acc, v0);
    acc8(acc, v1);
  }
  if (j + 4 <= end) {
    int s = col[j + g];
    uint4 v = *(const uint4*)(feat + (size_t)s * DIM + lg * 8);
    acc8(acc, v);
    j += 4;
  }
  int rem = end - j;
  if (g < rem) {
    int s = col[j + g];
    uint4 v = *(const uint4*)(feat + (size_t)s * DIM + lg * 8);
    acc8(acc, v);
  }

  // reduce across the 4 edge groups (lanes lg, 16+lg, 32+lg, 48+lg)
#pragma unroll
  for (int q = 0; q < 8; ++q) {
    acc[q] += __shfl_xor(acc[q], 16, 64);
    acc[q] += __shfl_xor(acc[q], 32, 64);
  }

  if (g == 0) {
    float inv = (end > beg) ? 1.0f / (float)(end - beg) : 0.f;
    union { uint32_t u[4]; uint4 v; } o;
#pragma unroll
    for (int q = 0; q < 4; ++q) {
      __hip_bfloat162 h;
      h.x = __float2bfloat16(acc[2 * q] * inv);
      h.y = __float2bfloat16(acc[2 * q + 1] * inv);
      o.u[q] = *(uint32_t*)&h;
    }
    *(uint4*)(agg + (size_t)node * DIM + lg * 8) = o.v;
  }
}

// ---------------- MFMA SAGE layer: h = relu([agg|x] @ WT^T + b) ----------------
__global__ __launch_bounds__(256) void k_sage(const bf16* __restrict__ agg,
                                              const bf16* __restrict__ xb,
                                              const bf16* __restrict__ WT,
                                              const float* __restrict__ bias,
                                              bf16* __restrict__ hout) {
  __shared__ char sA[NPB * 512];   // 32 KB
  const int tid = threadIdx.x;
  const int base = blockIdx.x * NPB;

#pragma unroll
  for (int i = 0; i < 8; ++i) {
    int c = tid + 256 * i;
    int row = c >> 5, kc = c & 31;
    int n = base + row;
    uint4 v = make_uint4(0, 0, 0, 0);
    if (n < N_NODES) {
      const bf16* sp = (kc < 16) ? (agg + (size_t)n * DIM + kc * 8)
                                 : (xb + (size_t)n * DIM + (kc - 16) * 8);
      v = *(const uint4*)sp;
    }
    int byte = (row * 512 + kc * 16) ^ ((row & 7) << 4);
    *(uint4*)(sA + byte) = v;
  }
  __syncthreads();

  const int w = tid >> 6, lane = tid & 63;
  const int j0 = w * 32;
  const int lrow = lane & 15, lk = lane >> 4;

  f32x4 acc[4][2];
#pragma unroll
  for (int mi = 0; mi < 4; ++mi)
#pragma unroll
    for (int ni = 0; ni < 2; ++ni)
      acc[mi][ni] = (f32x4){0.f, 0.f, 0.f, 0.f};

  for (int kt = 0; kt < 8; ++kt) {
    bfrag b0 = *(const bfrag*)(WT + (size_t)(j0 + lrow) * K2 + kt * 32 + lk * 8);
    bfrag b1 = *(const bfrag*)(WT + (size_t)(j0 + 16 + lrow) * K2 + kt * 32 + lk * 8);
#pragma unroll
    for (int mi = 0; mi < 4; ++mi) {
      int row = mi * 16 + lrow;
      int byte = (row * 512 + kt * 64 + lk * 16) ^ ((row & 7) << 4);
      bfrag a = *(const bfrag*)(sA + byte);
      acc[mi][0] = __builtin_amdgcn_mfma_f32_16x16x32_bf16(a, b0, acc[mi][0], 0, 0, 0);
      acc[mi][1] = __builtin_amdgcn_mfma_f32_16x16x32_bf16(a, b1, acc[mi][1], 0, 0, 0);
    }
  }

#pragma unroll
  for (int ni = 0; ni < 2; ++ni) {
    int colj = j0 + ni * 16 + lrow;
    float bv = bias[colj];
#pragma unroll
    for (int mi = 0; mi < 4; ++mi) {
#pragma unroll
      for (int r = 0; r < 4; ++r) {
        int n = base + mi * 16 + lk * 4 + r;
        if (n < N_NODES)
          hout[(size_t)n * DIM + colj] = __float2bfloat16(fmaxf(acc[mi][ni][r] + bv, 0.f));
      }
    }
  }
}

// ---------------- MFMA layer 1 + head ----------------
__global__ __launch_bounds__(256) void k_out(const bf16* __restrict__ agg,
                                             const bf16* __restrict__ xb,
                                             const bf16* __restrict__ WT,
                                             const float* __restrict__ bias,
                                             const bf16* __restrict__ WoT,
                                             const float* __restrict__ bo,
                                             float* __restrict__ out) {
  __shared__ char sA[NPB * 512];
  const int tid = threadIdx.x;
  const int base = blockIdx.x * NPB;

#pragma unroll
  for (int i = 0; i < 8; ++i) {
    int c = tid + 256 * i;
    int row = c >> 5, kc = c & 31;
    int n = base + row;
    uint4 v = make_uint4(0, 0, 0, 0);
    if (n < N_NODES) {
      const bf16* sp = (kc < 16) ? (agg + (size_t)n * DIM + kc * 8)
                                 : (xb + (size_t)n * DIM + (kc - 16) * 8);
      v = *(const uint4*)sp;
    }
    int byte = (row * 512 + kc * 16) ^ ((row & 7) << 4);
    *(uint4*)(sA + byte) = v;
  }
  __syncthreads();

  const int w = tid >> 6, lane = tid & 63;
  const int j0 = w * 32;
  const int lrow = lane & 15, lk = lane >> 4;

  f32x4 acc[4][2];
#pragma unroll
  for (int mi = 0; mi < 4; ++mi)
#pragma unroll
    for (int ni = 0; ni < 2; ++ni)
      acc[mi][ni] = (f32x4){0.f, 0.f, 0.f, 0.f};

  for (int kt = 0; kt < 8; ++kt) {
    bfrag b0 = *(const bfrag*)(WT + (size_t)(j0 + lrow) * K2 + kt * 32 + lk * 8);
    bfrag b1 = *(const bfrag*)(WT + (size_t)(j0 + 16 + lrow) * K2 + kt * 32 + lk * 8);
#pragma unroll
    for (int mi = 0; mi < 4; ++mi) {
      int row = mi * 16 + lrow;
      int byte = (row * 512 + kt * 64 + lk * 16) ^ ((row & 7) << 4);
      bfrag a = *(const bfrag*)(sA + byte);
      acc[mi][0] = __builtin_amdgcn_mfma_f32_16x16x32_bf16(a, b0, acc[mi][0], 0, 0, 0);
      acc[mi][1] = __builtin_amdgcn_mfma_f32_16x16x32_bf16(a, b1, acc[mi][1], 0, 0, 0);
    }
  }

  __syncthreads();
#pragma unroll
  for (int ni = 0; ni < 2; ++ni) {
    int colj = j0 + ni * 16 + lrow;
    float bv = bias[colj];
#pragma unroll
    for (int mi = 0; mi < 4; ++mi) {
#pragma unroll
      for (int r = 0; r < 4; ++r) {
        int row = mi * 16 + lk * 4 + r;
        float v = fmaxf(acc[mi][ni][r] + bv, 0.f);
        int byte = (row * 256 + colj * 2) ^ ((row & 7) << 4);
        *(bf16*)(sA + byte) = __float2bfloat16(v);
      }
    }
  }
  __syncthreads();

  const int jo = w * 16;
  f32x4 acc2[4];
#pragma unroll
  for (int mi = 0; mi < 4; ++mi) acc2[mi] = (f32x4){0.f, 0.f, 0.f, 0.f};

#pragma unroll
  for (int kt = 0; kt < 4; ++kt) {
    bfrag b = *(const bfrag*)(WoT + (size_t)(jo + lrow) * DIM + kt * 32 + lk * 8);
#pragma unroll
    for (int mi = 0; mi < 4; ++mi) {
      int row = mi * 16 + lrow;
      int byte = (row * 256 + kt * 64 + lk * 16) ^ ((row & 7) << 4);
      bfrag a = *(const bfrag*)(sA + byte);
      acc2[mi] = __builtin_amdgcn_mfma_f32_16x16x32_bf16(a, b, acc2[mi], 0, 0, 0);
    }
  }

  int colj = jo + lrow;
  float bv = bo[colj];
#pragma unroll
  for (int mi = 0; mi < 4; ++mi) {
#pragma unroll
    for (int r = 0; r < 4; ++r) {
      int n = base + mi * 16 + lk * 4 + r;
      if (n < N_NODES)
        out[(size_t)n * ODIM + colj] = 1.f / (1.f + __expf(-(acc2[mi][r] + bv)));
    }
  }
}

extern "C" void kernel_launch(void* const* d_in, const int* in_sizes, int n_in,
                              void* d_out, int out_size, void* d_ws, size_t ws_size,
                              hipStream_t stream) {
  const float* x     = (const float*)d_in[0];
  const int*   ei    = (const int*)d_in[1];
  const float* w_l0  = (const float*)d_in[2];
  const float* b_l0  = (const float*)d_in[3];
  const float* w_r0  = (const float*)d_in[4];
  const float* w_l1  = (const float*)d_in[5];
  const float* b_l1  = (const float*)d_in[6];
  const float* w_r1  = (const float*)d_in[7];
  const float* w_out = (const float*)d_in[8];
  const float* b_out = (const float*)d_in[9];
  float* out = (float*)d_out;

  const int* src = ei;
  const int* dst = ei + N_EDGES;

  char* ws = (char*)d_ws;
  int*  rowptr = (int*)(ws);
  int*  cursor = (int*)(ws + (512u << 10));
  int*  aux    = (int*)(ws + (1u << 20));
  int*  col    = (int*)(ws + (2u << 20));           // 6.4 MB
  bf16* WT0    = (bf16*)(ws + (9u << 20));
  bf16* WT1    = (bf16*)(ws + (9u << 20) + 65536);
  bf16* WoT    = (bf16*)(ws + (9u << 20) + 131072);
  bf16* aggb   = (bf16*)(ws + (10u << 20));         // 25.6 MB
  bf16* h0b    = (bf16*)(ws + (36ull << 20));       // 25.6 MB
  bf16* xb     = (bf16*)(ws + (62ull << 20));       // 25.6 MB

  k_cvt  <<<(N_NODES * DIM / 4 + 255) / 256, 256, 0, stream>>>(x, xb);
  k_prepw<<<(65536 + 8192 + 255) / 256, 256, 0, stream>>>(w_l0, w_r0, w_l1, w_r1, w_out,
                                                          WT0, WT1, WoT);

  hipMemsetAsync(rowptr, 0, (N_NODES + 1) * sizeof(int), stream);
  k_hist <<<(N_EDGES + 255) / 256, 256, 0, stream>>>(dst, rowptr);
  k_scan1<<<NSCAN, 256, 0, stream>>>(rowptr, aux);
  k_scan2<<<1, 128, 0, stream>>>(aux);
  k_scan3<<<(N_NODES + 255) / 256, 256, 0, stream>>>(rowptr, aux, cursor);
  k_fill <<<(N_EDGES + 255) / 256, 256, 0, stream>>>(src, dst, cursor, col);

  const int ablocks = (N_NODES * 64 + 255) / 256;
  const int gblocks = (N_NODES + NPB - 1) / NPB;

  k_agg <<<ablocks, 256, 0, stream>>>(xb, rowptr, col, aggb);
  k_sage<<<gblocks, 256, 0, stream>>>(aggb, xb, WT0, b_l0, h0b);

  k_agg<<<ablocks, 256, 0, stream>>>(h0b, rowptr, col, aggb);
  k_out<<<gblocks, 256, 0, stream>>>(aggb, h0b, WT1, b_l1, WoT, b_out, out);
}

// Round 5
// 354.298 us; speedup vs baseline: 16.3649x; 1.1273x over previous
//
#include <hip/hip_runtime.h>
#include <hip/hip_bf16.h>
#include <cstdint>

#define N_NODES 100000
#define N_EDGES 1600000
#define DIM 128
#define K2 256
#define ODIM 64
#define NPB 64
#define NB 3125          // buckets: dst>>5, 32 nodes each (3125*32 = 100000 exactly)
#define CAP 1024         // bucket capacity (mean 512, sigma ~23 -> +22 sigma head room)

typedef __hip_bfloat16 bf16;
typedef __attribute__((ext_vector_type(8))) short bfrag;   // 8 bf16 = 4 VGPRs
typedef __attribute__((ext_vector_type(4))) float f32x4;

// ---------------- bucket scatter: edge -> bucket(dst>>5), packed (src<<5)|dstLow ----------------
__global__ __launch_bounds__(256) void k_bucket(const int* __restrict__ src,
                                                const int* __restrict__ dst,
                                                int* __restrict__ bcnt,
                                                uint32_t* __restrict__ bdata) {
  int e = blockIdx.x * 256 + threadIdx.x;
  if (e >= N_EDGES) return;
  int d = dst[e];
  int key = d >> 5;
  int pos = atomicAdd(&bcnt[key], 1);
  if (pos < CAP)
    bdata[(size_t)key * CAP + pos] = ((uint32_t)src[e] << 5) | (uint32_t)(d & 31);
}

// ---------------- exclusive scan over NB bucket counts ----------------
__global__ __launch_bounds__(1024) void k_bscan(const int* __restrict__ bcnt,
                                                int* __restrict__ bbase) {
  __shared__ int sm[1024];
  const int t = threadIdx.x;
  const int i0 = t * 4;
  int v[4];
  int s = 0;
#pragma unroll
  for (int q = 0; q < 4; ++q) {
    int idx = i0 + q;
    v[q] = (idx < NB) ? bcnt[idx] : 0;
    s += v[q];
  }
  sm[t] = s;
  __syncthreads();
  for (int off = 1; off < 1024; off <<= 1) {
    int add = (t >= off) ? sm[t - off] : 0;
    __syncthreads();
    sm[t] += add;
    __syncthreads();
  }
  int p = sm[t] - s;   // exclusive prefix
#pragma unroll
  for (int q = 0; q < 4; ++q) {
    int idx = i0 + q;
    if (idx < NB) { bbase[idx] = p; p += v[q]; }
  }
}

// ---------------- per-bucket CSR rowptr + col fill (dense, LDS-local) ----------------
__global__ __launch_bounds__(256) void k_csr(const uint32_t* __restrict__ bdata,
                                             const int* __restrict__ bcnt,
                                             const int* __restrict__ bbase,
                                             int* __restrict__ rowptr,
                                             int* __restrict__ col) {
  __shared__ uint32_t ent[CAP];
  __shared__ int nc[32], noff[32], nc2[32];
  const int key = blockIdx.x, tid = threadIdx.x;
  const int C = min(bcnt[key], CAP);
  const int base = bbase[key];

  if (tid < 32) { nc[tid] = 0; nc2[tid] = 0; }
  __syncthreads();

  for (int i = tid; i < C; i += 256) {
    uint32_t e = bdata[(size_t)key * CAP + i];
    ent[i] = e;
    atomicAdd(&nc[e & 31], 1);
  }
  __syncthreads();

  if (tid == 0) {
    int run = 0;
#pragma unroll
    for (int n = 0; n < 32; ++n) { noff[n] = run; run += nc[n]; }
  }
  __syncthreads();

  if (tid < 32) rowptr[key * 32 + tid] = base + noff[tid];
  if (key == 0 && tid == 0) rowptr[N_NODES] = N_EDGES;

  for (int i = tid; i < C; i += 256) {
    uint32_t e = ent[i];
    int n = e & 31;
    int pos = atomicAdd(&nc2[n], 1);
    col[base + noff[n] + pos] = (int)(e >> 5);
  }
}

// ---------------- precompute: x -> bf16 ----------------
__global__ __launch_bounds__(256) void k_cvt(const float* __restrict__ x,
                                             bf16* __restrict__ xb) {
  int i = (blockIdx.x * 256 + threadIdx.x) * 4;
  if (i >= N_NODES * DIM) return;
  float4 v = *(const float4*)(x + i);
  bf16 t[4];
  t[0] = __float2bfloat16(v.x);
  t[1] = __float2bfloat16(v.y);
  t[2] = __float2bfloat16(v.z);
  t[3] = __float2bfloat16(v.w);
  *(uint2*)(xb + i) = *(uint2*)t;
}

// ---------------- precompute: pack weights transposed bf16 ----------------
__global__ __launch_bounds__(256) void k_prepw(const float* __restrict__ wl0,
                                               const float* __restrict__ wr0,
                                               const float* __restrict__ wl1,
                                               const float* __restrict__ wr1,
                                               const float* __restrict__ wo,
                                               bf16* __restrict__ WT0,
                                               bf16* __restrict__ WT1,
                                               bf16* __restrict__ WoT) {
  int g = blockIdx.x * 256 + threadIdx.x;
  if (g < 32768) {
    int j = g >> 8, k = g & 255;
    float v = (k < DIM) ? wl0[k * DIM + j] : wr0[(k - DIM) * DIM + j];
    WT0[g] = __float2bfloat16(v);
  } else if (g < 65536) {
    int gg = g - 32768;
    int j = gg >> 8, k = gg & 255;
    float v = (k < DIM) ? wl1[k * DIM + j] : wr1[(k - DIM) * DIM + j];
    WT1[gg] = __float2bfloat16(v);
  } else if (g < 65536 + 8192) {
    int gg = g - 65536;
    int j = gg >> 7, k = gg & 127;
    WoT[gg] = __float2bfloat16(wo[k * ODIM + j]);
  }
}

// ---------------- pull aggregation, 4 edges/wave in parallel + 2x unroll ----------------
__device__ __forceinline__ void acc8(float* acc, uint4 v) {
  acc[0] += __uint_as_float(v.x << 16);
  acc[1] += __uint_as_float(v.x & 0xFFFF0000u);
  acc[2] += __uint_as_float(v.y << 16);
  acc[3] += __uint_as_float(v.y & 0xFFFF0000u);
  acc[4] += __uint_as_float(v.z << 16);
  acc[5] += __uint_as_float(v.z & 0xFFFF0000u);
  acc[6] += __uint_as_float(v.w << 16);
  acc[7] += __uint_as_float(v.w & 0xFFFF0000u);
}

__global__ __launch_bounds__(256) void k_agg(const bf16* __restrict__ feat,
                                             const int* __restrict__ rowptr,
                                             const int* __restrict__ col,
                                             bf16* __restrict__ agg) {
  int gid = blockIdx.x * 256 + threadIdx.x;
  int node = gid >> 6;
  if (node >= N_NODES) return;
  int lane = gid & 63;
  int g = lane >> 4, lg = lane & 15;
  int beg = rowptr[node], end = rowptr[node + 1];

  float acc[8];
#pragma unroll
  for (int q = 0; q < 8; ++q) acc[q] = 0.f;

  int j = beg;
  for (; j + 8 <= end; j += 8) {
    int s0 = col[j + g];
    int s1 = col[j + 4 + g];
    uint4 v0 = *(const uint4*)(feat + (size_t)s0 * DIM + lg * 8);
    uint4 v1 = *(const uint4*)(feat + (size_t)s1 * DIM + lg * 8);
    acc8(acc, v0);
    acc8(acc, v1);
  }
  if (j + 4 <= end) {
    int s = col[j + g];
    uint4 v = *(const uint4*)(feat + (size_t)s * DIM + lg * 8);
    acc8(acc, v);
    j += 4;
  }
  int rem = end - j;
  if (g < rem) {
    int s = col[j + g];
    uint4 v = *(const uint4*)(feat + (size_t)s * DIM + lg * 8);
    acc8(acc, v);
  }

#pragma unroll
  for (int q = 0; q < 8; ++q) {
    acc[q] += __shfl_xor(acc[q], 16, 64);
    acc[q] += __shfl_xor(acc[q], 32, 64);
  }

  if (g == 0) {
    float inv = (end > beg) ? 1.0f / (float)(end - beg) : 0.f;
    union { uint32_t u[4]; uint4 v; } o;
#pragma unroll
    for (int q = 0; q < 4; ++q) {
      __hip_bfloat162 h;
      h.x = __float2bfloat16(acc[2 * q] * inv);
      h.y = __float2bfloat16(acc[2 * q + 1] * inv);
      o.u[q] = *(uint32_t*)&h;
    }
    *(uint4*)(agg + (size_t)node * DIM + lg * 8) = o.v;
  }
}

// ---------------- MFMA SAGE layer: h = relu([agg|x] @ WT^T + b) ----------------
__global__ __launch_bounds__(256) void k_sage(const bf16* __restrict__ agg,
                                              const bf16* __restrict__ xb,
                                              const bf16* __restrict__ WT,
                                              const float* __restrict__ bias,
                                              bf16* __restrict__ hout) {
  __shared__ char sA[NPB * 512];   // 32 KB
  const int tid = threadIdx.x;
  const int base = blockIdx.x * NPB;

#pragma unroll
  for (int i = 0; i < 8; ++i) {
    int c = tid + 256 * i;
    int row = c >> 5, kc = c & 31;
    int n = base + row;
    uint4 v = make_uint4(0, 0, 0, 0);
    if (n < N_NODES) {
      const bf16* sp = (kc < 16) ? (agg + (size_t)n * DIM + kc * 8)
                                 : (xb + (size_t)n * DIM + (kc - 16) * 8);
      v = *(const uint4*)sp;
    }
    int byte = (row * 512 + kc * 16) ^ ((row & 7) << 4);
    *(uint4*)(sA + byte) = v;
  }
  __syncthreads();

  const int w = tid >> 6, lane = tid & 63;
  const int j0 = w * 32;
  const int lrow = lane & 15, lk = lane >> 4;

  f32x4 acc[4][2];
#pragma unroll
  for (int mi = 0; mi < 4; ++mi)
#pragma unroll
    for (int ni = 0; ni < 2; ++ni)
      acc[mi][ni] = (f32x4){0.f, 0.f, 0.f, 0.f};

  for (int kt = 0; kt < 8; ++kt) {
    bfrag b0 = *(const bfrag*)(WT + (size_t)(j0 + lrow) * K2 + kt * 32 + lk * 8);
    bfrag b1 = *(const bfrag*)(WT + (size_t)(j0 + 16 + lrow) * K2 + kt * 32 + lk * 8);
#pragma unroll
    for (int mi = 0; mi < 4; ++mi) {
      int row = mi * 16 + lrow;
      int byte = (row * 512 + kt * 64 + lk * 16) ^ ((row & 7) << 4);
      bfrag a = *(const bfrag*)(sA + byte);
      acc[mi][0] = __builtin_amdgcn_mfma_f32_16x16x32_bf16(a, b0, acc[mi][0], 0, 0, 0);
      acc[mi][1] = __builtin_amdgcn_mfma_f32_16x16x32_bf16(a, b1, acc[mi][1], 0, 0, 0);
    }
  }

#pragma unroll
  for (int ni = 0; ni < 2; ++ni) {
    int colj = j0 + ni * 16 + lrow;
    float bv = bias[colj];
#pragma unroll
    for (int mi = 0; mi < 4; ++mi) {
#pragma unroll
      for (int r = 0; r < 4; ++r) {
        int n = base + mi * 16 + lk * 4 + r;
        if (n < N_NODES)
          hout[(size_t)n * DIM + colj] = __float2bfloat16(fmaxf(acc[mi][ni][r] + bv, 0.f));
      }
    }
  }
}

// ---------------- MFMA layer 1 + head ----------------
__global__ __launch_bounds__(256) void k_out(const bf16* __restrict__ agg,
                                             const bf16* __restrict__ xb,
                                             const bf16* __restrict__ WT,
                                             const float* __restrict__ bias,
                                             const bf16* __restrict__ WoT,
                                             const float* __restrict__ bo,
                                             float* __restrict__ out) {
  __shared__ char sA[NPB * 512];
  const int tid = threadIdx.x;
  const int base = blockIdx.x * NPB;

#pragma unroll
  for (int i = 0; i < 8; ++i) {
    int c = tid + 256 * i;
    int row = c >> 5, kc = c & 31;
    int n = base + row;
    uint4 v = make_uint4(0, 0, 0, 0);
    if (n < N_NODES) {
      const bf16* sp = (kc < 16) ? (agg + (size_t)n * DIM + kc * 8)
                                 : (xb + (size_t)n * DIM + (kc - 16) * 8);
      v = *(const uint4*)sp;
    }
    int byte = (row * 512 + kc * 16) ^ ((row & 7) << 4);
    *(uint4*)(sA + byte) = v;
  }
  __syncthreads();

  const int w = tid >> 6, lane = tid & 63;
  const int j0 = w * 32;
  const int lrow = lane & 15, lk = lane >> 4;

  f32x4 acc[4][2];
#pragma unroll
  for (int mi = 0; mi < 4; ++mi)
#pragma unroll
    for (int ni = 0; ni < 2; ++ni)
      acc[mi][ni] = (f32x4){0.f, 0.f, 0.f, 0.f};

  for (int kt = 0; kt < 8; ++kt) {
    bfrag b0 = *(const bfrag*)(WT + (size_t)(j0 + lrow) * K2 + kt * 32 + lk * 8);
    bfrag b1 = *(const bfrag*)(WT + (size_t)(j0 + 16 + lrow) * K2 + kt * 32 + lk * 8);
#pragma unroll
    for (int mi = 0; mi < 4; ++mi) {
      int row = mi * 16 + lrow;
      int byte = (row * 512 + kt * 64 + lk * 16) ^ ((row & 7) << 4);
      bfrag a = *(const bfrag*)(sA + byte);
      acc[mi][0] = __builtin_amdgcn_mfma_f32_16x16x32_bf16(a, b0, acc[mi][0], 0, 0, 0);
      acc[mi][1] = __builtin_amdgcn_mfma_f32_16x16x32_bf16(a, b1, acc[mi][1], 0, 0, 0);
    }
  }

  __syncthreads();
#pragma unroll
  for (int ni = 0; ni < 2; ++ni) {
    int colj = j0 + ni * 16 + lrow;
    float bv = bias[colj];
#pragma unroll
    for (int mi = 0; mi < 4; ++mi) {
#pragma unroll
      for (int r = 0; r < 4; ++r) {
        int row = mi * 16 + lk * 4 + r;
        float v = fmaxf(acc[mi][ni][r] + bv, 0.f);
        int byte = (row * 256 + colj * 2) ^ ((row & 7) << 4);
        *(bf16*)(sA + byte) = __float2bfloat16(v);
      }
    }
  }
  __syncthreads();

  const int jo = w * 16;
  f32x4 acc2[4];
#pragma unroll
  for (int mi = 0; mi < 4; ++mi) acc2[mi] = (f32x4){0.f, 0.f, 0.f, 0.f};

#pragma unroll
  for (int kt = 0; kt < 4; ++kt) {
    bfrag b = *(const bfrag*)(WoT + (size_t)(jo + lrow) * DIM + kt * 32 + lk * 8);
#pragma unroll
    for (int mi = 0; mi < 4; ++mi) {
      int row = mi * 16 + lrow;
      int byte = (row * 256 + kt * 64 + lk * 16) ^ ((row & 7) << 4);
      bfrag a = *(const bfrag*)(sA + byte);
      acc2[mi] = __builtin_amdgcn_mfma_f32_16x16x32_bf16(a, b, acc2[mi], 0, 0, 0);
    }
  }

  int colj = jo + lrow;
  float bv = bo[colj];
#pragma unroll
  for (int mi = 0; mi < 4; ++mi) {
#pragma unroll
    for (int r = 0; r < 4; ++r) {
      int n = base + mi * 16 + lk * 4 + r;
      if (n < N_NODES)
        out[(size_t)n * ODIM + colj] = 1.f / (1.f + __expf(-(acc2[mi][r] + bv)));
    }
  }
}

extern "C" void kernel_launch(void* const* d_in, const int* in_sizes, int n_in,
                              void* d_out, int out_size, void* d_ws, size_t ws_size,
                              hipStream_t stream) {
  const float* x     = (const float*)d_in[0];
  const int*   ei    = (const int*)d_in[1];
  const float* w_l0  = (const float*)d_in[2];
  const float* b_l0  = (const float*)d_in[3];
  const float* w_r0  = (const float*)d_in[4];
  const float* w_l1  = (const float*)d_in[5];
  const float* b_l1  = (const float*)d_in[6];
  const float* w_r1  = (const float*)d_in[7];
  const float* w_out = (const float*)d_in[8];
  const float* b_out = (const float*)d_in[9];
  float* out = (float*)d_out;

  const int* src = ei;
  const int* dst = ei + N_EDGES;

  char* ws = (char*)d_ws;
  int*      rowptr = (int*)(ws);                          // 400,004 B
  int*      bcnt   = (int*)(ws + (512u << 10));           // 12.5 KB
  int*      bbase  = (int*)(ws + (576u << 10));           // 12.5 KB
  int*      col    = (int*)(ws + (1u << 20));             // 6.4 MB
  uint32_t* bdata  = (uint32_t*)(ws + (8u << 20));        // 12.8 MB
  bf16*     WT0    = (bf16*)(ws + (21u << 20));           // 64 KB
  bf16*     WT1    = (bf16*)(ws + (21u << 20) + 65536);   // 64 KB
  bf16*     WoT    = (bf16*)(ws + (21u << 20) + 131072);  // 16 KB
  bf16*     aggb   = (bf16*)(ws + (22ull << 20));         // 25.6 MB
  bf16*     h0b    = (bf16*)(ws + (48ull << 20));         // 25.6 MB
  bf16*     xb     = (bf16*)(ws + (74ull << 20));         // 25.6 MB (~99.6 MB total)

  // --- precompute (independent of CSR) ---
  k_cvt  <<<(N_NODES * DIM / 4 + 255) / 256, 256, 0, stream>>>(x, xb);
  k_prepw<<<(65536 + 8192 + 255) / 256, 256, 0, stream>>>(w_l0, w_r0, w_l1, w_r1, w_out,
                                                          WT0, WT1, WoT);

  // --- CSR build via bucket counting sort ---
  hipMemsetAsync(bcnt, 0, NB * sizeof(int), stream);
  k_bucket<<<(N_EDGES + 255) / 256, 256, 0, stream>>>(src, dst, bcnt, bdata);
  k_bscan <<<1, 1024, 0, stream>>>(bcnt, bbase);
  k_csr   <<<NB, 256, 0, stream>>>(bdata, bcnt, bbase, rowptr, col);

  const int ablocks = (N_NODES * 64 + 255) / 256;
  const int gblocks = (N_NODES + NPB - 1) / NPB;

  // --- layer 0 ---
  k_agg <<<ablocks, 256, 0, stream>>>(xb, rowptr, col, aggb);
  k_sage<<<gblocks, 256, 0, stream>>>(aggb, xb, WT0, b_l0, h0b);

  // --- layer 1 + head ---
  k_agg<<<ablocks, 256, 0, stream>>>(h0b, rowptr, col, aggb);
  k_out<<<gblocks, 256, 0, stream>>>(aggb, h0b, WT1, b_l1, WoT, b_out, out);
}

// Round 6
// 295.713 us; speedup vs baseline: 19.6069x; 1.1981x over previous
//
#include <hip/hip_runtime.h>
#include <hip/hip_bf16.h>
#include <cstdint>

#define N_NODES 100000
#define N_EDGES 1600000
#define DIM 128
#define K2 256
#define ODIM 64
#define NPB 64
#define NB 3125          // buckets: dst>>5, 32 nodes each (3125*32 = 100000 exactly)
#define NREP 8           // bucket replicas (one per XCD via blockIdx&7 heuristic)
#define CAP 160          // per-replica bucket capacity (mean 64, +12 sigma)

typedef __hip_bfloat16 bf16;
typedef __attribute__((ext_vector_type(8))) short bfrag;   // 8 bf16 = 4 VGPRs
typedef __attribute__((ext_vector_type(4))) float f32x4;

// ---------------- bucket scatter: edge -> replica(blockIdx&7), bucket(dst>>5) ----------------
__global__ __launch_bounds__(256) void k_bucket(const int* __restrict__ src,
                                                const int* __restrict__ dst,
                                                int* __restrict__ bcnt,
                                                uint32_t* __restrict__ bdata) {
  const int rep = blockIdx.x & (NREP - 1);
  int e0 = (blockIdx.x * 256 + threadIdx.x) * 4;
  if (e0 >= N_EDGES) return;
  int4 s4 = *(const int4*)(src + e0);
  int4 d4 = *(const int4*)(dst + e0);
  int ss[4] = {s4.x, s4.y, s4.z, s4.w};
  int dd[4] = {d4.x, d4.y, d4.z, d4.w};
#pragma unroll
  for (int q = 0; q < 4; ++q) {
    int key = dd[q] >> 5;
    int pos = atomicAdd(&bcnt[rep * NB + key], 1);
    if (pos < CAP)
      bdata[((size_t)rep * NB + key) * CAP + pos] =
          ((uint32_t)ss[q] << 5) | (uint32_t)(dd[q] & 31);
  }
}

// ---------------- exclusive scan over per-key totals (sum of replicas) ----------------
__global__ __launch_bounds__(1024) void k_bscan(const int* __restrict__ bcnt,
                                                int* __restrict__ bbase) {
  __shared__ int sm[1024];
  const int t = threadIdx.x;
  const int i0 = t * 4;
  int v[4];
  int s = 0;
#pragma unroll
  for (int q = 0; q < 4; ++q) {
    int idx = i0 + q;
    int tot = 0;
    if (idx < NB) {
#pragma unroll
      for (int r = 0; r < NREP; ++r) tot += min(bcnt[r * NB + idx], CAP);
    }
    v[q] = tot;
    s += tot;
  }
  sm[t] = s;
  __syncthreads();
  for (int off = 1; off < 1024; off <<= 1) {
    int add = (t >= off) ? sm[t - off] : 0;
    __syncthreads();
    sm[t] += add;
    __syncthreads();
  }
  int p = sm[t] - s;   // exclusive prefix
#pragma unroll
  for (int q = 0; q < 4; ++q) {
    int idx = i0 + q;
    if (idx < NB) { bbase[idx] = p; p += v[q]; }
  }
}

// ---------------- per-bucket CSR rowptr + col fill (merge 8 replicas, LDS-local) ----------------
__global__ __launch_bounds__(256) void k_csr(const uint32_t* __restrict__ bdata,
                                             const int* __restrict__ bcnt,
                                             const int* __restrict__ bbase,
                                             int* __restrict__ rowptr,
                                             int* __restrict__ col) {
  __shared__ uint32_t ent[NREP * CAP];
  __shared__ int cr[NREP + 1];
  __shared__ int nc[32], noff[32], nc2[32];
  const int key = blockIdx.x, tid = threadIdx.x;
  const int base = bbase[key];

  if (tid < 32) { nc[tid] = 0; nc2[tid] = 0; }
  if (tid == 0) {
    int run = 0;
#pragma unroll
    for (int r = 0; r < NREP; ++r) {
      cr[r] = run;
      run += min(bcnt[r * NB + key], CAP);
    }
    cr[NREP] = run;
  }
  __syncthreads();

  const int total = cr[NREP];
#pragma unroll
  for (int r = 0; r < NREP; ++r) {
    int o = cr[r], c = cr[r + 1] - o;
    for (int i = tid; i < c; i += 256) {
      uint32_t e = bdata[((size_t)r * NB + key) * CAP + i];
      ent[o + i] = e;
      atomicAdd(&nc[e & 31], 1);
    }
  }
  __syncthreads();

  if (tid == 0) {
    int run = 0;
#pragma unroll
    for (int n = 0; n < 32; ++n) { noff[n] = run; run += nc[n]; }
  }
  __syncthreads();

  if (tid < 32) rowptr[key * 32 + tid] = base + noff[tid];
  if (key == 0 && tid == 0) rowptr[N_NODES] = N_EDGES;

  for (int i = tid; i < total; i += 256) {
    uint32_t e = ent[i];
    int n = e & 31;
    int pos = atomicAdd(&nc2[n], 1);
    col[base + noff[n] + pos] = (int)(e >> 5);
  }
}

// ---------------- precompute: x -> bf16 ----------------
__global__ __launch_bounds__(256) void k_cvt(const float* __restrict__ x,
                                             bf16* __restrict__ xb) {
  int i = (blockIdx.x * 256 + threadIdx.x) * 4;
  if (i >= N_NODES * DIM) return;
  float4 v = *(const float4*)(x + i);
  bf16 t[4];
  t[0] = __float2bfloat16(v.x);
  t[1] = __float2bfloat16(v.y);
  t[2] = __float2bfloat16(v.z);
  t[3] = __float2bfloat16(v.w);
  *(uint2*)(xb + i) = *(uint2*)t;
}

// ---------------- precompute: pack weights transposed bf16 ----------------
__global__ __launch_bounds__(256) void k_prepw(const float* __restrict__ wl0,
                                               const float* __restrict__ wr0,
                                               const float* __restrict__ wl1,
                                               const float* __restrict__ wr1,
                                               const float* __restrict__ wo,
                                               bf16* __restrict__ WT0,
                                               bf16* __restrict__ WT1,
                                               bf16* __restrict__ WoT) {
  int g = blockIdx.x * 256 + threadIdx.x;
  if (g < 32768) {
    int j = g >> 8, k = g & 255;
    float v = (k < DIM) ? wl0[k * DIM + j] : wr0[(k - DIM) * DIM + j];
    WT0[g] = __float2bfloat16(v);
  } else if (g < 65536) {
    int gg = g - 32768;
    int j = gg >> 8, k = gg & 255;
    float v = (k < DIM) ? wl1[k * DIM + j] : wr1[(k - DIM) * DIM + j];
    WT1[gg] = __float2bfloat16(v);
  } else if (g < 65536 + 8192) {
    int gg = g - 65536;
    int j = gg >> 7, k = gg & 127;
    WoT[gg] = __float2bfloat16(wo[k * ODIM + j]);
  }
}

// ---------------- pull aggregation, 4 edges/wave in parallel + 2x unroll ----------------
__device__ __forceinline__ void acc8(float* acc, uint4 v) {
  acc[0] += __uint_as_float(v.x << 16);
  acc[1] += __uint_as_float(v.x & 0xFFFF0000u);
  acc[2] += __uint_as_float(v.y << 16);
  acc[3] += __uint_as_float(v.y & 0xFFFF0000u);
  acc[4] += __uint_as_float(v.z << 16);
  acc[5] += __uint_as_float(v.z & 0xFFFF0000u);
  acc[6] += __uint_as_float(v.w << 16);
  acc[7] += __uint_as_float(v.w & 0xFFFF0000u);
}

__global__ __launch_bounds__(256) void k_agg(const bf16* __restrict__ feat,
                                             const int* __restrict__ rowptr,
                                             const int* __restrict__ col,
                                             bf16* __restrict__ agg) {
  int gid = blockIdx.x * 256 + threadIdx.x;
  int node = gid >> 6;
  if (node >= N_NODES) return;
  int lane = gid & 63;
  int g = lane >> 4, lg = lane & 15;
  int beg = rowptr[node], end = rowptr[node + 1];

  float acc[8];
#pragma unroll
  for (int q = 0; q < 8; ++q) acc[q] = 0.f;

  int j = beg;
  for (; j + 8 <= end; j += 8) {
    int s0 = col[j + g];
    int s1 = col[j + 4 + g];
    uint4 v0 = *(const uint4*)(feat + (size_t)s0 * DIM + lg * 8);
    uint4 v1 = *(const uint4*)(feat + (size_t)s1 * DIM + lg * 8);
    acc8(acc, v0);
    acc8(acc, v1);
  }
  if (j + 4 <= end) {
    int s = col[j + g];
    uint4 v = *(const uint4*)(feat + (size_t)s * DIM + lg * 8);
    acc8(acc, v);
    j += 4;
  }
  int rem = end - j;
  if (g < rem) {
    int s = col[j + g];
    uint4 v = *(const uint4*)(feat + (size_t)s * DIM + lg * 8);
    acc8(acc, v);
  }

#pragma unroll
  for (int q = 0; q < 8; ++q) {
    acc[q] += __shfl_xor(acc[q], 16, 64);
    acc[q] += __shfl_xor(acc[q], 32, 64);
  }

  if (g == 0) {
    float inv = (end > beg) ? 1.0f / (float)(end - beg) : 0.f;
    union { uint32_t u[4]; uint4 v; } o;
#pragma unroll
    for (int q = 0; q < 4; ++q) {
      __hip_bfloat162 h;
      h.x = __float2bfloat16(acc[2 * q] * inv);
      h.y = __float2bfloat16(acc[2 * q + 1] * inv);
      o.u[q] = *(uint32_t*)&h;
    }
    *(uint4*)(agg + (size_t)node * DIM + lg * 8) = o.v;
  }
}

// ---------------- MFMA SAGE layer: h = relu([agg|x] @ WT^T + b) ----------------
__global__ __launch_bounds__(256) void k_sage(const bf16* __restrict__ agg,
                                              const bf16* __restrict__ xb,
                                              const bf16* __restrict__ WT,
                                              const float* __restrict__ bias,
                                              bf16* __restrict__ hout) {
  __shared__ char sA[NPB * 512];   // 32 KB
  const int tid = threadIdx.x;
  const int base = blockIdx.x * NPB;

#pragma unroll
  for (int i = 0; i < 8; ++i) {
    int c = tid + 256 * i;
    int row = c >> 5, kc = c & 31;
    int n = base + row;
    uint4 v = make_uint4(0, 0, 0, 0);
    if (n < N_NODES) {
      const bf16* sp = (kc < 16) ? (agg + (size_t)n * DIM + kc * 8)
                                 : (xb + (size_t)n * DIM + (kc - 16) * 8);
      v = *(const uint4*)sp;
    }
    int byte = (row * 512 + kc * 16) ^ ((row & 7) << 4);
    *(uint4*)(sA + byte) = v;
  }
  __syncthreads();

  const int w = tid >> 6, lane = tid & 63;
  const int j0 = w * 32;
  const int lrow = lane & 15, lk = lane >> 4;

  f32x4 acc[4][2];
#pragma unroll
  for (int mi = 0; mi < 4; ++mi)
#pragma unroll
    for (int ni = 0; ni < 2; ++ni)
      acc[mi][ni] = (f32x4){0.f, 0.f, 0.f, 0.f};

  for (int kt = 0; kt < 8; ++kt) {
    bfrag b0 = *(const bfrag*)(WT + (size_t)(j0 + lrow) * K2 + kt * 32 + lk * 8);
    bfrag b1 = *(const bfrag*)(WT + (size_t)(j0 + 16 + lrow) * K2 + kt * 32 + lk * 8);
#pragma unroll
    for (int mi = 0; mi < 4; ++mi) {
      int row = mi * 16 + lrow;
      int byte = (row * 512 + kt * 64 + lk * 16) ^ ((row & 7) << 4);
      bfrag a = *(const bfrag*)(sA + byte);
      acc[mi][0] = __builtin_amdgcn_mfma_f32_16x16x32_bf16(a, b0, acc[mi][0], 0, 0, 0);
      acc[mi][1] = __builtin_amdgcn_mfma_f32_16x16x32_bf16(a, b1, acc[mi][1], 0, 0, 0);
    }
  }

#pragma unroll
  for (int ni = 0; ni < 2; ++ni) {
    int colj = j0 + ni * 16 + lrow;
    float bv = bias[colj];
#pragma unroll
    for (int mi = 0; mi < 4; ++mi) {
#pragma unroll
      for (int r = 0; r < 4; ++r) {
        int n = base + mi * 16 + lk * 4 + r;
        if (n < N_NODES)
          hout[(size_t)n * DIM + colj] = __float2bfloat16(fmaxf(acc[mi][ni][r] + bv, 0.f));
      }
    }
  }
}

// ---------------- MFMA layer 1 + head ----------------
__global__ __launch_bounds__(256) void k_out(const bf16* __restrict__ agg,
                                             const bf16* __restrict__ xb,
                                             const bf16* __restrict__ WT,
                                             const float* __restrict__ bias,
                                             const bf16* __restrict__ WoT,
                                             const float* __restrict__ bo,
                                             float* __restrict__ out) {
  __shared__ char sA[NPB * 512];
  const int tid = threadIdx.x;
  const int base = blockIdx.x * NPB;

#pragma unroll
  for (int i = 0; i < 8; ++i) {
    int c = tid + 256 * i;
    int row = c >> 5, kc = c & 31;
    int n = base + row;
    uint4 v = make_uint4(0, 0, 0, 0);
    if (n < N_NODES) {
      const bf16* sp = (kc < 16) ? (agg + (size_t)n * DIM + kc * 8)
                                 : (xb + (size_t)n * DIM + (kc - 16) * 8);
      v = *(const uint4*)sp;
    }
    int byte = (row * 512 + kc * 16) ^ ((row & 7) << 4);
    *(uint4*)(sA + byte) = v;
  }
  __syncthreads();

  const int w = tid >> 6, lane = tid & 63;
  const int j0 = w * 32;
  const int lrow = lane & 15, lk = lane >> 4;

  f32x4 acc[4][2];
#pragma unroll
  for (int mi = 0; mi < 4; ++mi)
#pragma unroll
    for (int ni = 0; ni < 2; ++ni)
      acc[mi][ni] = (f32x4){0.f, 0.f, 0.f, 0.f};

  for (int kt = 0; kt < 8; ++kt) {
    bfrag b0 = *(const bfrag*)(WT + (size_t)(j0 + lrow) * K2 + kt * 32 + lk * 8);
    bfrag b1 = *(const bfrag*)(WT + (size_t)(j0 + 16 + lrow) * K2 + kt * 32 + lk * 8);
#pragma unroll
    for (int mi = 0; mi < 4; ++mi) {
      int row = mi * 16 + lrow;
      int byte = (row * 512 + kt * 64 + lk * 16) ^ ((row & 7) << 4);
      bfrag a = *(const bfrag*)(sA + byte);
      acc[mi][0] = __builtin_amdgcn_mfma_f32_16x16x32_bf16(a, b0, acc[mi][0], 0, 0, 0);
      acc[mi][1] = __builtin_amdgcn_mfma_f32_16x16x32_bf16(a, b1, acc[mi][1], 0, 0, 0);
    }
  }

  __syncthreads();
#pragma unroll
  for (int ni = 0; ni < 2; ++ni) {
    int colj = j0 + ni * 16 + lrow;
    float bv = bias[colj];
#pragma unroll
    for (int mi = 0; mi < 4; ++mi) {
#pragma unroll
      for (int r = 0; r < 4; ++r) {
        int row = mi * 16 + lk * 4 + r;
        float v = fmaxf(acc[mi][ni][r] + bv, 0.f);
        int byte = (row * 256 + colj * 2) ^ ((row & 7) << 4);
        *(bf16*)(sA + byte) = __float2bfloat16(v);
      }
    }
  }
  __syncthreads();

  const int jo = w * 16;
  f32x4 acc2[4];
#pragma unroll
  for (int mi = 0; mi < 4; ++mi) acc2[mi] = (f32x4){0.f, 0.f, 0.f, 0.f};

#pragma unroll
  for (int kt = 0; kt < 4; ++kt) {
    bfrag b = *(const bfrag*)(WoT + (size_t)(jo + lrow) * DIM + kt * 32 + lk * 8);
#pragma unroll
    for (int mi = 0; mi < 4; ++mi) {
      int row = mi * 16 + lrow;
      int byte = (row * 256 + kt * 64 + lk * 16) ^ ((row & 7) << 4);
      bfrag a = *(const bfrag*)(sA + byte);
      acc2[mi] = __builtin_amdgcn_mfma_f32_16x16x32_bf16(a, b, acc2[mi], 0, 0, 0);
    }
  }

  int colj = jo + lrow;
  float bv = bo[colj];
#pragma unroll
  for (int mi = 0; mi < 4; ++mi) {
#pragma unroll
    for (int r = 0; r < 4; ++r) {
      int n = base + mi * 16 + lk * 4 + r;
      if (n < N_NODES)
        out[(size_t)n * ODIM + colj] = 1.f / (1.f + __expf(-(acc2[mi][r] + bv)));
    }
  }
}

extern "C" void kernel_launch(void* const* d_in, const int* in_sizes, int n_in,
                              void* d_out, int out_size, void* d_ws, size_t ws_size,
                              hipStream_t stream) {
  const float* x     = (const float*)d_in[0];
  const int*   ei    = (const int*)d_in[1];
  const float* w_l0  = (const float*)d_in[2];
  const float* b_l0  = (const float*)d_in[3];
  const float* w_r0  = (const float*)d_in[4];
  const float* w_l1  = (const float*)d_in[5];
  const float* b_l1  = (const float*)d_in[6];
  const float* w_r1  = (const float*)d_in[7];
  const float* w_out = (const float*)d_in[8];
  const float* b_out = (const float*)d_in[9];
  float* out = (float*)d_out;

  const int* src = ei;
  const int* dst = ei + N_EDGES;

  char* ws = (char*)d_ws;
  int*      rowptr = (int*)(ws);                          // 400,004 B
  int*      bcnt   = (int*)(ws + (512u << 10));           // 100 KB (8 x 3125)
  int*      bbase  = (int*)(ws + (768u << 10));           // 12.5 KB
  int*      col    = (int*)(ws + (1u << 20));             // 6.4 MB
  uint32_t* bdata  = (uint32_t*)(ws + (8u << 20));        // 16 MB (8 x 3125 x 160)
  bf16*     WT0    = (bf16*)(ws + (24u << 20));           // 64 KB
  bf16*     WT1    = (bf16*)(ws + (24u << 20) + 65536);   // 64 KB
  bf16*     WoT    = (bf16*)(ws + (24u << 20) + 131072);  // 16 KB
  bf16*     aggb   = (bf16*)(ws + (25ull << 20));         // 25.6 MB
  bf16*     h0b    = (bf16*)(ws + (51ull << 20));         // 25.6 MB
  bf16*     xb     = (bf16*)(ws + (77ull << 20));         // 25.6 MB (~102.6 MB total)

  // --- precompute (independent of CSR) ---
  k_cvt  <<<(N_NODES * DIM / 4 + 255) / 256, 256, 0, stream>>>(x, xb);
  k_prepw<<<(65536 + 8192 + 255) / 256, 256, 0, stream>>>(w_l0, w_r0, w_l1, w_r1, w_out,
                                                          WT0, WT1, WoT);

  // --- CSR build via replicated bucket counting sort ---
  hipMemsetAsync(bcnt, 0, NREP * NB * sizeof(int), stream);
  k_bucket<<<(N_EDGES / 4 + 255) / 256, 256, 0, stream>>>(src, dst, bcnt, bdata);
  k_bscan <<<1, 1024, 0, stream>>>(bcnt, bbase);
  k_csr   <<<NB, 256, 0, stream>>>(bdata, bcnt, bbase, rowptr, col);

  const int ablocks = (N_NODES * 64 + 255) / 256;
  const int gblocks = (N_NODES + NPB - 1) / NPB;

  // --- layer 0 ---
  k_agg <<<ablocks, 256, 0, stream>>>(xb, rowptr, col, aggb);
  k_sage<<<gblocks, 256, 0, stream>>>(aggb, xb, WT0, b_l0, h0b);

  // --- layer 1 + head ---
  k_agg<<<ablocks, 256, 0, stream>>>(h0b, rowptr, col, aggb);
  k_out<<<gblocks, 256, 0, stream>>>(aggb, h0b, WT1, b_l1, WoT, b_out, out);
}

// Round 7
// 250.463 us; speedup vs baseline: 23.1493x; 1.1807x over previous
//
#include <hip/hip_runtime.h>
#include <hip/hip_bf16.h>
#include <cstdint>

#define N_NODES 100000
#define N_EDGES 1600000
#define DIM 128
#define K2 256
#define ODIM 64
#define NPB 64
#define CB 98            // coarse buckets: dst>>10 (1024 nodes each)
#define NREP 8           // replicas (one per XCD via blockIdx&7 heuristic)
#define CAP1 2560        // per (rep,bucket) capacity: mean ~2048, +11 sigma
#define EPB 4096         // edges per k_bucket block

typedef __hip_bfloat16 bf16;
typedef __attribute__((ext_vector_type(8))) short bfrag;   // 8 bf16 = 4 VGPRs
typedef __attribute__((ext_vector_type(4))) float f32x4;

// ---------------- bucket binning: LDS-sort 4096 edges by coarse key, bulk-append ----------------
__global__ __launch_bounds__(1024) void k_bucket(const int* __restrict__ src,
                                                 const int* __restrict__ dst,
                                                 int* __restrict__ gcur,
                                                 uint32_t* __restrict__ bdata) {
  __shared__ int hist[CB], hbase[CB], hcur[CB], gstart[CB];
  __shared__ uint32_t ent[EPB];
  __shared__ uint8_t kslot[EPB];
  const int tid = threadIdx.x;
  const int rep = blockIdx.x & (NREP - 1);
  const int e0 = blockIdx.x * EPB;
  const int cnt = min(EPB, N_EDGES - e0);

  if (tid < CB) { hist[tid] = 0; hcur[tid] = 0; }
  __syncthreads();

  const int me0 = e0 + tid * 4;
  int ss[4], dd[4];
  int nmine = max(0, min(4, N_EDGES - me0));
  if (nmine == 4) {
    *(int4*)ss = *(const int4*)(src + me0);
    *(int4*)dd = *(const int4*)(dst + me0);
  } else {
    for (int q = 0; q < nmine; ++q) { ss[q] = src[me0 + q]; dd[q] = dst[me0 + q]; }
  }

#pragma unroll
  for (int q = 0; q < 4; ++q)
    if (q < nmine) atomicAdd(&hist[dd[q] >> 10], 1);
  __syncthreads();

  if (tid == 0) {
    int run = 0;
    for (int b = 0; b < CB; ++b) { hbase[b] = run; run += hist[b]; }
  }
  __syncthreads();

#pragma unroll
  for (int q = 0; q < 4; ++q)
    if (q < nmine) {
      int key = dd[q] >> 10;
      int r = atomicAdd(&hcur[key], 1);
      int p = hbase[key] + r;
      ent[p] = ((uint32_t)ss[q] << 10) | (uint32_t)(dd[q] & 1023);
      kslot[p] = (uint8_t)key;
    }
  __syncthreads();

  if (tid < CB && hist[tid] > 0)
    gstart[tid] = atomicAdd(&gcur[rep * CB + tid], hist[tid]);
  __syncthreads();

  for (int i = tid; i < cnt; i += 1024) {
    int k = kslot[i];
    int pos = gstart[k] + (i - hbase[k]);
    if (pos < CAP1)
      bdata[((size_t)(rep * CB + k)) * CAP1 + pos] = ent[i];
  }
}

// ---------------- per-coarse-bucket CSR: 1024-node hist + scan + rank scatter ----------------
__global__ __launch_bounds__(256) void k_csr(const uint32_t* __restrict__ bdata,
                                             const int* __restrict__ gcur,
                                             int* __restrict__ rowptr,
                                             int* __restrict__ col) {
  __shared__ int nc[1024], noff[1024];
  __shared__ int red[256];
  __shared__ int sz[NREP];
  const int b = blockIdx.x, tid = threadIdx.x;

  if (tid < NREP) sz[tid] = min(gcur[tid * CB + b], CAP1);

  // global base = sum of all segments of buckets < b
  int part = 0;
  for (int i = tid; i < NREP * b; i += 256) {
    int bp = i >> 3, r = i & 7;
    part += min(gcur[r * CB + bp], CAP1);
  }
  red[tid] = part;
  __syncthreads();
  for (int off = 128; off > 0; off >>= 1) {
    if (tid < off) red[tid] += red[tid + off];
    __syncthreads();
  }
  const int base = red[0];
  __syncthreads();

  for (int i = tid; i < 1024; i += 256) nc[i] = 0;
  __syncthreads();

  // pass 1: histogram over 1024 nodes
  for (int r = 0; r < NREP; ++r) {
    int c = sz[r];
    const uint32_t* seg = bdata + ((size_t)(r * CB + b)) * CAP1;
    for (int i = tid; i < c; i += 256)
      atomicAdd(&nc[seg[i] & 1023], 1);
  }
  __syncthreads();

  // exclusive scan of nc[1024] -> noff[1024]
  int loc[4], s = 0;
#pragma unroll
  for (int q = 0; q < 4; ++q) { loc[q] = nc[tid * 4 + q]; s += loc[q]; }
  red[tid] = s;
  __syncthreads();
  for (int off = 1; off < 256; off <<= 1) {
    int add = (tid >= off) ? red[tid - off] : 0;
    __syncthreads();
    red[tid] += add;
    __syncthreads();
  }
  int p = red[tid] - s;
#pragma unroll
  for (int q = 0; q < 4; ++q) { noff[tid * 4 + q] = p; p += loc[q]; }
  __syncthreads();

  for (int i = tid; i < 1024; i += 256) {
    int n = b * 1024 + i;
    if (n < N_NODES) rowptr[n] = base + noff[i];
  }
  if (b == 0 && tid == 0) rowptr[N_NODES] = N_EDGES;

  for (int i = tid; i < 1024; i += 256) nc[i] = 0;
  __syncthreads();

  // pass 2: rank + scatter
  for (int r = 0; r < NREP; ++r) {
    int c = sz[r];
    const uint32_t* seg = bdata + ((size_t)(r * CB + b)) * CAP1;
    for (int i = tid; i < c; i += 256) {
      uint32_t e = seg[i];
      int n = e & 1023;
      int pos = atomicAdd(&nc[n], 1);
      col[base + noff[n] + pos] = (int)(e >> 10);
    }
  }
}

// ---------------- precompute: x -> bf16 ----------------
__global__ __launch_bounds__(256) void k_cvt(const float* __restrict__ x,
                                             bf16* __restrict__ xb) {
  int i = (blockIdx.x * 256 + threadIdx.x) * 4;
  if (i >= N_NODES * DIM) return;
  float4 v = *(const float4*)(x + i);
  bf16 t[4];
  t[0] = __float2bfloat16(v.x);
  t[1] = __float2bfloat16(v.y);
  t[2] = __float2bfloat16(v.z);
  t[3] = __float2bfloat16(v.w);
  *(uint2*)(xb + i) = *(uint2*)t;
}

// ---------------- precompute: pack weights transposed bf16 ----------------
__global__ __launch_bounds__(256) void k_prepw(const float* __restrict__ wl0,
                                               const float* __restrict__ wr0,
                                               const float* __restrict__ wl1,
                                               const float* __restrict__ wr1,
                                               const float* __restrict__ wo,
                                               bf16* __restrict__ WT0,
                                               bf16* __restrict__ WT1,
                                               bf16* __restrict__ WoT) {
  int g = blockIdx.x * 256 + threadIdx.x;
  if (g < 32768) {
    int j = g >> 8, k = g & 255;
    float v = (k < DIM) ? wl0[k * DIM + j] : wr0[(k - DIM) * DIM + j];
    WT0[g] = __float2bfloat16(v);
  } else if (g < 65536) {
    int gg = g - 32768;
    int j = gg >> 8, k = gg & 255;
    float v = (k < DIM) ? wl1[k * DIM + j] : wr1[(k - DIM) * DIM + j];
    WT1[gg] = __float2bfloat16(v);
  } else if (g < 65536 + 8192) {
    int gg = g - 65536;
    int j = gg >> 7, k = gg & 127;
    WoT[gg] = __float2bfloat16(wo[k * ODIM + j]);
  }
}

// ---------------- pull aggregation, 4 edges/wave in parallel + 2x unroll ----------------
__device__ __forceinline__ void acc8(float* acc, uint4 v) {
  acc[0] += __uint_as_float(v.x << 16);
  acc[1] += __uint_as_float(v.x & 0xFFFF0000u);
  acc[2] += __uint_as_float(v.y << 16);
  acc[3] += __uint_as_float(v.y & 0xFFFF0000u);
  acc[4] += __uint_as_float(v.z << 16);
  acc[5] += __uint_as_float(v.z & 0xFFFF0000u);
  acc[6] += __uint_as_float(v.w << 16);
  acc[7] += __uint_as_float(v.w & 0xFFFF0000u);
}

__global__ __launch_bounds__(256) void k_agg(const bf16* __restrict__ feat,
                                             const int* __restrict__ rowptr,
                                             const int* __restrict__ col,
                                             bf16* __restrict__ agg) {
  int gid = blockIdx.x * 256 + threadIdx.x;
  int node = gid >> 6;
  if (node >= N_NODES) return;
  int lane = gid & 63;
  int g = lane >> 4, lg = lane & 15;
  int beg = rowptr[node], end = rowptr[node + 1];

  float acc[8];
#pragma unroll
  for (int q = 0; q < 8; ++q) acc[q] = 0.f;

  int j = beg;
  for (; j + 8 <= end; j += 8) {
    int s0 = col[j + g];
    int s1 = col[j + 4 + g];
    uint4 v0 = *(const uint4*)(feat + (size_t)s0 * DIM + lg * 8);
    uint4 v1 = *(const uint4*)(feat + (size_t)s1 * DIM + lg * 8);
    acc8(acc, v0);
    acc8(acc, v1);
  }
  if (j + 4 <= end) {
    int s = col[j + g];
    uint4 v = *(const uint4*)(feat + (size_t)s * DIM + lg * 8);
    acc8(acc, v);
    j += 4;
  }
  int rem = end - j;
  if (g < rem) {
    int s = col[j + g];
    uint4 v = *(const uint4*)(feat + (size_t)s * DIM + lg * 8);
    acc8(acc, v);
  }

#pragma unroll
  for (int q = 0; q < 8; ++q) {
    acc[q] += __shfl_xor(acc[q], 16, 64);
    acc[q] += __shfl_xor(acc[q], 32, 64);
  }

  if (g == 0) {
    float inv = (end > beg) ? 1.0f / (float)(end - beg) : 0.f;
    union { uint32_t u[4]; uint4 v; } o;
#pragma unroll
    for (int q = 0; q < 4; ++q) {
      __hip_bfloat162 h;
      h.x = __float2bfloat16(acc[2 * q] * inv);
      h.y = __float2bfloat16(acc[2 * q + 1] * inv);
      o.u[q] = *(uint32_t*)&h;
    }
    *(uint4*)(agg + (size_t)node * DIM + lg * 8) = o.v;
  }
}

// ---------------- MFMA SAGE layer: h = relu([agg|x] @ WT^T + b) ----------------
__global__ __launch_bounds__(256) void k_sage(const bf16* __restrict__ agg,
                                              const bf16* __restrict__ xb,
                                              const bf16* __restrict__ WT,
                                              const float* __restrict__ bias,
                                              bf16* __restrict__ hout) {
  __shared__ char sA[NPB * 512];   // 32 KB
  const int tid = threadIdx.x;
  const int base = blockIdx.x * NPB;

#pragma unroll
  for (int i = 0; i < 8; ++i) {
    int c = tid + 256 * i;
    int row = c >> 5, kc = c & 31;
    int n = base + row;
    uint4 v = make_uint4(0, 0, 0, 0);
    if (n < N_NODES) {
      const bf16* sp = (kc < 16) ? (agg + (size_t)n * DIM + kc * 8)
                                 : (xb + (size_t)n * DIM + (kc - 16) * 8);
      v = *(const uint4*)sp;
    }
    int byte = (row * 512 + kc * 16) ^ ((row & 7) << 4);
    *(uint4*)(sA + byte) = v;
  }
  __syncthreads();

  const int w = tid >> 6, lane = tid & 63;
  const int j0 = w * 32;
  const int lrow = lane & 15, lk = lane >> 4;

  f32x4 acc[4][2];
#pragma unroll
  for (int mi = 0; mi < 4; ++mi)
#pragma unroll
    for (int ni = 0; ni < 2; ++ni)
      acc[mi][ni] = (f32x4){0.f, 0.f, 0.f, 0.f};

  for (int kt = 0; kt < 8; ++kt) {
    bfrag b0 = *(const bfrag*)(WT + (size_t)(j0 + lrow) * K2 + kt * 32 + lk * 8);
    bfrag b1 = *(const bfrag*)(WT + (size_t)(j0 + 16 + lrow) * K2 + kt * 32 + lk * 8);
#pragma unroll
    for (int mi = 0; mi < 4; ++mi) {
      int row = mi * 16 + lrow;
      int byte = (row * 512 + kt * 64 + lk * 16) ^ ((row & 7) << 4);
      bfrag a = *(const bfrag*)(sA + byte);
      acc[mi][0] = __builtin_amdgcn_mfma_f32_16x16x32_bf16(a, b0, acc[mi][0], 0, 0, 0);
      acc[mi][1] = __builtin_amdgcn_mfma_f32_16x16x32_bf16(a, b1, acc[mi][1], 0, 0, 0);
    }
  }

#pragma unroll
  for (int ni = 0; ni < 2; ++ni) {
    int colj = j0 + ni * 16 + lrow;
    float bv = bias[colj];
#pragma unroll
    for (int mi = 0; mi < 4; ++mi) {
#pragma unroll
      for (int r = 0; r < 4; ++r) {
        int n = base + mi * 16 + lk * 4 + r;
        if (n < N_NODES)
          hout[(size_t)n * DIM + colj] = __float2bfloat16(fmaxf(acc[mi][ni][r] + bv, 0.f));
      }
    }
  }
}

// ---------------- MFMA layer 1 + head ----------------
__global__ __launch_bounds__(256) void k_out(const bf16* __restrict__ agg,
                                             const bf16* __restrict__ xb,
                                             const bf16* __restrict__ WT,
                                             const float* __restrict__ bias,
                                             const bf16* __restrict__ WoT,
                                             const float* __restrict__ bo,
                                             float* __restrict__ out) {
  __shared__ char sA[NPB * 512];
  const int tid = threadIdx.x;
  const int base = blockIdx.x * NPB;

#pragma unroll
  for (int i = 0; i < 8; ++i) {
    int c = tid + 256 * i;
    int row = c >> 5, kc = c & 31;
    int n = base + row;
    uint4 v = make_uint4(0, 0, 0, 0);
    if (n < N_NODES) {
      const bf16* sp = (kc < 16) ? (agg + (size_t)n * DIM + kc * 8)
                                 : (xb + (size_t)n * DIM + (kc - 16) * 8);
      v = *(const uint4*)sp;
    }
    int byte = (row * 512 + kc * 16) ^ ((row & 7) << 4);
    *(uint4*)(sA + byte) = v;
  }
  __syncthreads();

  const int w = tid >> 6, lane = tid & 63;
  const int j0 = w * 32;
  const int lrow = lane & 15, lk = lane >> 4;

  f32x4 acc[4][2];
#pragma unroll
  for (int mi = 0; mi < 4; ++mi)
#pragma unroll
    for (int ni = 0; ni < 2; ++ni)
      acc[mi][ni] = (f32x4){0.f, 0.f, 0.f, 0.f};

  for (int kt = 0; kt < 8; ++kt) {
    bfrag b0 = *(const bfrag*)(WT + (size_t)(j0 + lrow) * K2 + kt * 32 + lk * 8);
    bfrag b1 = *(const bfrag*)(WT + (size_t)(j0 + 16 + lrow) * K2 + kt * 32 + lk * 8);
#pragma unroll
    for (int mi = 0; mi < 4; ++mi) {
      int row = mi * 16 + lrow;
      int byte = (row * 512 + kt * 64 + lk * 16) ^ ((row & 7) << 4);
      bfrag a = *(const bfrag*)(sA + byte);
      acc[mi][0] = __builtin_amdgcn_mfma_f32_16x16x32_bf16(a, b0, acc[mi][0], 0, 0, 0);
      acc[mi][1] = __builtin_amdgcn_mfma_f32_16x16x32_bf16(a, b1, acc[mi][1], 0, 0, 0);
    }
  }

  __syncthreads();
#pragma unroll
  for (int ni = 0; ni < 2; ++ni) {
    int colj = j0 + ni * 16 + lrow;
    float bv = bias[colj];
#pragma unroll
    for (int mi = 0; mi < 4; ++mi) {
#pragma unroll
      for (int r = 0; r < 4; ++r) {
        int row = mi * 16 + lk * 4 + r;
        float v = fmaxf(acc[mi][ni][r] + bv, 0.f);
        int byte = (row * 256 + colj * 2) ^ ((row & 7) << 4);
        *(bf16*)(sA + byte) = __float2bfloat16(v);
      }
    }
  }
  __syncthreads();

  const int jo = w * 16;
  f32x4 acc2[4];
#pragma unroll
  for (int mi = 0; mi < 4; ++mi) acc2[mi] = (f32x4){0.f, 0.f, 0.f, 0.f};

#pragma unroll
  for (int kt = 0; kt < 4; ++kt) {
    bfrag b = *(const bfrag*)(WoT + (size_t)(jo + lrow) * DIM + kt * 32 + lk * 8);
#pragma unroll
    for (int mi = 0; mi < 4; ++mi) {
      int row = mi * 16 + lrow;
      int byte = (row * 256 + kt * 64 + lk * 16) ^ ((row & 7) << 4);
      bfrag a = *(const bfrag*)(sA + byte);
      acc2[mi] = __builtin_amdgcn_mfma_f32_16x16x32_bf16(a, b, acc2[mi], 0, 0, 0);
    }
  }

  int colj = jo + lrow;
  float bv = bo[colj];
#pragma unroll
  for (int mi = 0; mi < 4; ++mi) {
#pragma unroll
    for (int r = 0; r < 4; ++r) {
      int n = base + mi * 16 + lk * 4 + r;
      if (n < N_NODES)
        out[(size_t)n * ODIM + colj] = 1.f / (1.f + __expf(-(acc2[mi][r] + bv)));
    }
  }
}

extern "C" void kernel_launch(void* const* d_in, const int* in_sizes, int n_in,
                              void* d_out, int out_size, void* d_ws, size_t ws_size,
                              hipStream_t stream) {
  const float* x     = (const float*)d_in[0];
  const int*   ei    = (const int*)d_in[1];
  const float* w_l0  = (const float*)d_in[2];
  const float* b_l0  = (const float*)d_in[3];
  const float* w_r0  = (const float*)d_in[4];
  const float* w_l1  = (const float*)d_in[5];
  const float* b_l1  = (const float*)d_in[6];
  const float* w_r1  = (const float*)d_in[7];
  const float* w_out = (const float*)d_in[8];
  const float* b_out = (const float*)d_in[9];
  float* out = (float*)d_out;

  const int* src = ei;
  const int* dst = ei + N_EDGES;

  char* ws = (char*)d_ws;
  int*      rowptr = (int*)(ws);                          // 400,004 B
  int*      gcur   = (int*)(ws + (512u << 10));           // 3,136 B
  int*      col    = (int*)(ws + (1u << 20));             // 6.4 MB
  uint32_t* bdata  = (uint32_t*)(ws + (8u << 20));        // 8.03 MB (8 x 98 x 2560)
  bf16*     WT0    = (bf16*)(ws + (17u << 20));           // 64 KB
  bf16*     WT1    = (bf16*)(ws + (17u << 20) + 65536);   // 64 KB
  bf16*     WoT    = (bf16*)(ws + (17u << 20) + 131072);  // 16 KB
  bf16*     aggb   = (bf16*)(ws + (18ull << 20));         // 25.6 MB
  bf16*     h0b    = (bf16*)(ws + (44ull << 20));         // 25.6 MB
  bf16*     xb     = (bf16*)(ws + (70ull << 20));         // 25.6 MB (~95.6 MB total)

  // --- precompute (independent of CSR) ---
  k_cvt  <<<(N_NODES * DIM / 4 + 255) / 256, 256, 0, stream>>>(x, xb);
  k_prepw<<<(65536 + 8192 + 255) / 256, 256, 0, stream>>>(w_l0, w_r0, w_l1, w_r1, w_out,
                                                          WT0, WT1, WoT);

  // --- CSR build: block-binned bucket sort -> per-bucket CSR ---
  hipMemsetAsync(gcur, 0, NREP * CB * sizeof(int), stream);
  k_bucket<<<(N_EDGES + EPB - 1) / EPB, 1024, 0, stream>>>(src, dst, gcur, bdata);
  k_csr   <<<CB, 256, 0, stream>>>(bdata, gcur, rowptr, col);

  const int ablocks = (N_NODES * 64 + 255) / 256;
  const int gblocks = (N_NODES + NPB - 1) / NPB;

  // --- layer 0 ---
  k_agg <<<ablocks, 256, 0, stream>>>(xb, rowptr, col, aggb);
  k_sage<<<gblocks, 256, 0, stream>>>(aggb, xb, WT0, b_l0, h0b);

  // --- layer 1 + head ---
  k_agg<<<ablocks, 256, 0, stream>>>(h0b, rowptr, col, aggb);
  k_out<<<gblocks, 256, 0, stream>>>(aggb, h0b, WT1, b_l1, WoT, b_out, out);
}